// Round 3
// baseline (1652.981 us; speedup 1.0000x reference)
//
#include <hip/hip_runtime.h>
#include <hip/hip_bf16.h>
#include <hip/hip_fp16.h>
#include <math.h>

#define N_NODES 100000
#define N_EDGES 3200000
#define N_GRAPHS 512
#define BN_EPS 1e-5f
#define NB_BUCKET ((N_NODES + 63) / 64)   // 1563 buckets of 64 nodes

// ---------------- bucketed CSR build ----------------
// pass 1: per-bucket edge counts
__global__ void k_bucket_count(const int* __restrict__ dst, int* __restrict__ bcnt) {
    int e = blockIdx.x * blockDim.x + threadIdx.x;
    if (e < N_EDGES) atomicAdd(&bcnt[dst[e] >> 6], 1);
}

// pass 2: exclusive scan of 1563 bucket counts (single block, 2 per thread)
__global__ void k_bucket_scan(const int* __restrict__ bcnt, int* __restrict__ bbase,
                              int* __restrict__ offs) {
    __shared__ int sd[1024];
    int t = threadIdx.x;
    int v0 = (2 * t < NB_BUCKET) ? bcnt[2 * t] : 0;
    int v1 = (2 * t + 1 < NB_BUCKET) ? bcnt[2 * t + 1] : 0;
    sd[t] = v0 + v1;
    __syncthreads();
    for (int off = 1; off < 1024; off <<= 1) {
        int tmp = (t >= off) ? sd[t - off] : 0;
        __syncthreads();
        sd[t] += tmp;
        __syncthreads();
    }
    int excl = sd[t] - (v0 + v1);
    if (2 * t < NB_BUCKET) bbase[2 * t] = excl;
    if (2 * t + 1 < NB_BUCKET) bbase[2 * t + 1] = excl + v0;
    if (t == 0) { bbase[NB_BUCKET] = N_EDGES; offs[N_NODES] = N_EDGES; }
}

// pass 3: scatter edges into bucket-contiguous store, packed (src<<6)|dst_lo
__global__ void k_bucket_fill(const int* __restrict__ src, const int* __restrict__ dst,
                              const int* __restrict__ bbase, int* __restrict__ bcur,
                              int* __restrict__ store) {
    int e = blockIdx.x * blockDim.x + threadIdx.x;
    if (e < N_EDGES) {
        int d = dst[e];
        int b = d >> 6;
        int pos = bbase[b] + atomicAdd(&bcur[b], 1);
        store[pos] = (src[e] << 6) | (d & 63);
    }
}

// pass 4: one block per bucket; LDS counters/scan -> offs, dis, csr
__global__ void k_csr_build(const int* __restrict__ bbase, const int* __restrict__ store,
                            int* __restrict__ offs, float* __restrict__ dis,
                            int* __restrict__ csr) {
    int b = blockIdx.x;
    int n0 = b << 6;
    int nn = min(64, N_NODES - n0);
    int e0 = bbase[b], e1 = bbase[b + 1];
    __shared__ int cnt[64], loc[64], cur[64];
    if (threadIdx.x < 64) cnt[threadIdx.x] = 0;
    __syncthreads();
    for (int e = e0 + threadIdx.x; e < e1; e += blockDim.x)
        atomicAdd(&cnt[store[e] & 63], 1);
    __syncthreads();
    if (threadIdx.x < 64) {
        int c = cnt[threadIdx.x];
        int inc = c;
#pragma unroll
        for (int off = 1; off < 64; off <<= 1) {
            int u = __shfl_up(inc, off, 64);
            if (threadIdx.x >= off) inc += u;
        }
        int ex = inc - c;
        loc[threadIdx.x] = ex;
        cur[threadIdx.x] = ex;   // cursor starts at local offset
        if (threadIdx.x < nn) {
            offs[n0 + threadIdx.x] = e0 + ex;
            dis[n0 + threadIdx.x] = rsqrtf(1.0f + (float)c);
        }
    }
    __syncthreads();
    for (int e = e0 + threadIdx.x; e < e1; e += blockDim.x) {
        int p = store[e];
        int pos = e0 + atomicAdd(&cur[p & 63], 1);
        csr[pos] = p >> 6;
    }
}

// ---------------- layer-1 matmul (no preceding BN), fp16 out, dis-prescaled ----------------
// writes zero row at n == N_NODES (zero-row trick for agg tails)
template <int FIN, int FOUT>
__global__ void k_mm_h(const float* __restrict__ h, const float* __restrict__ W,
                       const float* __restrict__ dis, __half* __restrict__ out) {
    __shared__ float sW[FIN * FOUT];
    for (int i = threadIdx.x; i < FIN * FOUT; i += blockDim.x) sW[i] = W[i];
    __syncthreads();
    int gid = blockIdx.x * blockDim.x + threadIdx.x;
    if (gid >= (N_NODES + 1) * FOUT) return;
    int n = gid / FOUT, f = gid % FOUT;
    if (n == N_NODES) { out[gid] = __float2half(0.f); return; }
    float acc = 0.f;
#pragma unroll
    for (int i = 0; i < FIN; ++i) acc += h[n * FIN + i] * sW[i * FOUT + f];
    out[gid] = __float2half(acc * dis[n]);
}

// ---------------- fused bn(relu(conv+bias)) @ W matmul ----------------
// h_bn = a*relu(conv+b)+c ;  h_bn@W = relu(conv+b) @ (diag(a)W) + c@W
template <int FIN, int FOUT>
__global__ void k_mm_fused(const float* __restrict__ conv, const float* __restrict__ bias,
                           const float* __restrict__ bnp, const float* __restrict__ W,
                           const float* __restrict__ dis, __half* __restrict__ out) {
    __shared__ float sW[FIN * FOUT];
    __shared__ float scb[FOUT];
    for (int i = threadIdx.x; i < FIN * FOUT; i += blockDim.x)
        sW[i] = bnp[i / FOUT] * W[i];
    if (threadIdx.x < FOUT) {
        float cb = 0.f;
#pragma unroll
        for (int r = 0; r < FIN; ++r) cb += bnp[FIN + r] * W[r * FOUT + threadIdx.x];
        scb[threadIdx.x] = cb;
    }
    __syncthreads();
    int gid = blockIdx.x * blockDim.x + threadIdx.x;
    if (gid >= (N_NODES + 1) * FOUT) return;
    int n = gid / FOUT, f = gid % FOUT;
    if (n == N_NODES) { out[gid] = __float2half(0.f); return; }
    float acc = scb[f];
#pragma unroll
    for (int i = 0; i < FIN; ++i) {
        float y = conv[n * FIN + i] + bias[i];
        y = y > 0.f ? y : 0.f;
        acc += y * sW[i * FOUT + f];
    }
    out[gid] = __float2half(acc * dis[n]);
}

// ---------------- GCN aggregation (wave-per-node, half4 gather, zero-row tails) ----------------

struct alignas(8) h4 { __half2 a, b; };

template <int FOUT>
__global__ void k_agg_v3(const __half* __restrict__ hWd, const int* __restrict__ offs,
                         const int* __restrict__ csr, const float* __restrict__ dis,
                         float* __restrict__ out) {
    constexpr int LPE = FOUT / 4;     // lanes per edge-row
    constexpr int EPI = 64 / LPE;     // edges per wave-iteration
    int wave = threadIdx.x >> 6;
    int lane = threadIdx.x & 63;
    int node = blockIdx.x * (blockDim.x >> 6) + wave;
    if (node >= N_NODES) return;
    int chunk = lane % LPE;
    int eg    = lane / LPE;

    int e0 = offs[node], e1 = offs[node + 1];
    float dn = dis[node];
    float ax = 0.f, ay = 0.f, az = 0.f, aw = 0.f;
    const __half* hp = hWd + (size_t)chunk * 4;

    for (int e = e0 + eg; e < e1; e += 4 * EPI) {
        int s0 = csr[e];
        int s1 = (e + EPI     < e1) ? csr[e + EPI]     : N_NODES;
        int s2 = (e + 2 * EPI < e1) ? csr[e + 2 * EPI] : N_NODES;
        int s3 = (e + 3 * EPI < e1) ? csr[e + 3 * EPI] : N_NODES;
        h4 v0 = *(const h4*)(hp + (size_t)s0 * FOUT);
        h4 v1 = *(const h4*)(hp + (size_t)s1 * FOUT);
        h4 v2 = *(const h4*)(hp + (size_t)s2 * FOUT);
        h4 v3 = *(const h4*)(hp + (size_t)s3 * FOUT);
        ax += __low2float(v0.a) + __low2float(v1.a) + __low2float(v2.a) + __low2float(v3.a);
        ay += __high2float(v0.a) + __high2float(v1.a) + __high2float(v2.a) + __high2float(v3.a);
        az += __low2float(v0.b) + __low2float(v1.b) + __low2float(v2.b) + __low2float(v3.b);
        aw += __high2float(v0.b) + __high2float(v1.b) + __high2float(v2.b) + __high2float(v3.b);
    }
    if (eg == 0) {  // self-loop
        h4 v = *(const h4*)(hp + (size_t)node * FOUT);
        ax += __low2float(v.a);
        ay += __high2float(v.a);
        az += __low2float(v.b);
        aw += __high2float(v.b);
    }
#pragma unroll
    for (int off = LPE; off < 64; off <<= 1) {
        ax += __shfl_xor(ax, off, 64);
        ay += __shfl_xor(ay, off, 64);
        az += __shfl_xor(az, off, 64);
        aw += __shfl_xor(aw, off, 64);
    }
    if (lane < LPE) {
        float4 r = make_float4(dn * ax, dn * ay, dn * az, dn * aw);
        *(float4*)(out + (size_t)node * FOUT + chunk * 4) = r;
    }
}

// ---------------- BN stats over y = relu(conv + bias) ----------------

template <int FOUT>
__global__ void k_stats(const float* __restrict__ conv, const float* __restrict__ bias,
                        float* __restrict__ stats) {
    constexpr int GP = 256 / FOUT;
    int f = threadIdx.x % FOUT, g = threadIdx.x / FOUT;
    float bf = bias[f];
    float s = 0.f, s2 = 0.f;
    for (int n = blockIdx.x * GP + g; n < N_NODES; n += gridDim.x * GP) {
        float y = conv[n * FOUT + f] + bf;
        y = y > 0.f ? y : 0.f;
        s += y;
        s2 += y * y;
    }
    __shared__ float ls[256], ls2[256];
    ls[threadIdx.x] = s;
    ls2[threadIdx.x] = s2;
    __syncthreads();
    if (g == 0) {
        for (int gg = 1; gg < GP; ++gg) {
            s += ls[gg * FOUT + f];
            s2 += ls2[gg * FOUT + f];
        }
        atomicAdd(&stats[f], s);
        atomicAdd(&stats[FOUT + f], s2);
    }
}

template <int FOUT>
__global__ void k_bnprep(const float* __restrict__ stats, const float* __restrict__ gamma,
                         const float* __restrict__ beta, float* __restrict__ bnp) {
    int f = threadIdx.x;
    if (f >= FOUT) return;
    float inv_n = 1.0f / (float)N_NODES;
    float m = stats[f] * inv_n;
    float v = stats[FOUT + f] * inv_n - m * m;
    float a = gamma[f] * rsqrtf(v + BN_EPS);
    bnp[f] = a;
    bnp[FOUT + f] = beta[f] - m * a;
}

// ---------------- pool with fused bn(relu(conv+b)) + head ----------------

__device__ __forceinline__ int lower_bound_dev(const int* __restrict__ a, int val) {
    int lo = 0, hi = N_NODES;
    while (lo < hi) {
        int mid = (lo + hi) >> 1;
        if (a[mid] < val) lo = mid + 1; else hi = mid;
    }
    return lo;
}

__global__ void k_pool(const float* __restrict__ conv, const int* __restrict__ batch,
                       const float* __restrict__ bias, const float* __restrict__ bnp,
                       float* __restrict__ pooled) {
    int g = blockIdx.x;       // 0..511
    int f = threadIdx.x;      // 0..127
    int s = lower_bound_dev(batch, g);
    int e = lower_bound_dev(batch, g + 1);
    float bf = bias[f];
    float mx = -INFINITY, mn = INFINITY;
    for (int n = s; n < e; ++n) {
        float y = conv[n * 128 + f] + bf;
        y = y > 0.f ? y : 0.f;
        mx = fmaxf(mx, y);
        mn = fminf(mn, y);
    }
    float a = bnp[f], c = bnp[128 + f];
    float r;
    if (e > s) r = (a >= 0.f) ? (a * mx + c) : (a * mn + c);
    else r = -INFINITY;
    pooled[g * 128 + f] = r;
}

__global__ void k_head(const float* __restrict__ pooled, const float* __restrict__ Wl,
                       const float* __restrict__ bl, float* __restrict__ out) {
    int g = blockIdx.x * blockDim.x + threadIdx.x;
    if (g >= N_GRAPHS) return;
    float l0 = bl[0], l1 = bl[1], l2 = bl[2];
    for (int i = 0; i < 128; ++i) {
        float p = pooled[g * 128 + i];
        l0 += p * Wl[i * 3 + 0];
        l1 += p * Wl[i * 3 + 1];
        l2 += p * Wl[i * 3 + 2];
    }
    float mx = fmaxf(l0, fmaxf(l1, l2));
    float lse = mx + logf(expf(l0 - mx) + expf(l1 - mx) + expf(l2 - mx));
    out[g * 3 + 0] = l0 - lse;
    out[g * 3 + 1] = l1 - lse;
    out[g * 3 + 2] = l2 - lse;
}

// ---------------- launch ----------------

extern "C" void kernel_launch(void* const* d_in, const int* in_sizes, int n_in,
                              void* d_out, int out_size, void* d_ws, size_t ws_size,
                              hipStream_t stream) {
    const float* x   = (const float*)d_in[0];
    const int* ei    = (const int*)d_in[1];
    const int* src   = ei;
    const int* dst   = ei + N_EDGES;
    const int* batch = (const int*)d_in[2];
    const float *W1 = (const float*)d_in[3],  *b1 = (const float*)d_in[4];
    const float *g1 = (const float*)d_in[5],  *be1 = (const float*)d_in[6];
    const float *W2 = (const float*)d_in[7],  *b2 = (const float*)d_in[8];
    const float *g2 = (const float*)d_in[9],  *be2 = (const float*)d_in[10];
    const float *W3 = (const float*)d_in[11], *b3 = (const float*)d_in[12];
    const float *g3 = (const float*)d_in[13], *be3 = (const float*)d_in[14];
    const float *Wl = (const float*)d_in[15], *bl = (const float*)d_in[16];
    float* out = (float*)d_out;

    // workspace carve (4-byte units). bcnt/bcur/stats first -> single memset.
    int* base = (int*)d_ws;
    size_t o = 0;
    int* bcnt    = base + o; o += NB_BUCKET;
    int* bcur    = base + o; o += NB_BUCKET;
    float* stats1 = (float*)(base + o); o += 256;
    float* stats2 = (float*)(base + o); o += 256;
    float* stats3 = (float*)(base + o); o += 256;
    size_t zero_words = o;                       // everything above gets memset to 0
    int* bbase   = base + o; o += NB_BUCKET + 1;
    float* bnp1  = (float*)(base + o); o += 256;
    float* bnp2  = (float*)(base + o); o += 256;
    float* bnp3  = (float*)(base + o); o += 256;
    int* offs    = base + o; o += N_NODES + 1;
    int* store   = base + o; o += N_EDGES;
    int* csr     = base + o; o += N_EDGES;
    float* dis   = (float*)(base + o); o += N_NODES;
    float* pooled= (float*)(base + o); o += (size_t)N_GRAPHS * 128;
    __half* bufH = (__half*)(base + o); o += (size_t)(N_NODES + 1) * 64;  // (N+1)*128 halfs
    float* bufC  = (float*)(base + o); o += (size_t)N_NODES * 128;
    if (ws_size < o * 4) return;

    const int TB = 256;
    const int gridE = (N_EDGES + TB - 1) / TB;
    const int gridAgg = (N_NODES + 3) / 4;        // 4 waves/block, wave-per-node

    hipMemsetAsync(base, 0, zero_words * 4, stream);

    // CSR build (bucketed)
    k_bucket_count<<<gridE, TB, 0, stream>>>(dst, bcnt);
    k_bucket_scan<<<1, 1024, 0, stream>>>(bcnt, bbase, offs);
    k_bucket_fill<<<gridE, TB, 0, stream>>>(src, dst, bbase, bcur, store);
    k_csr_build<<<NB_BUCKET, TB, 0, stream>>>(bbase, store, offs, dis, csr);

    // ---- layer 1: 2 -> 8 ----
    {
        const int g8 = ((N_NODES + 1) * 8 + TB - 1) / TB;
        k_mm_h<2, 8><<<g8, TB, 0, stream>>>(x, W1, dis, bufH);
        k_agg_v3<8><<<gridAgg, TB, 0, stream>>>(bufH, offs, csr, dis, bufC);
        k_stats<8><<<256, 256, 0, stream>>>(bufC, b1, stats1);
        k_bnprep<8><<<1, 8, 0, stream>>>(stats1, g1, be1, bnp1);
    }
    // ---- layer 2: 8 -> 32 ----
    {
        const int g32 = ((N_NODES + 1) * 32 + TB - 1) / TB;
        k_mm_fused<8, 32><<<g32, TB, 0, stream>>>(bufC, b1, bnp1, W2, dis, bufH);
        k_agg_v3<32><<<gridAgg, TB, 0, stream>>>(bufH, offs, csr, dis, bufC);
        k_stats<32><<<256, 256, 0, stream>>>(bufC, b2, stats2);
        k_bnprep<32><<<1, 32, 0, stream>>>(stats2, g2, be2, bnp2);
    }
    // ---- layer 3: 32 -> 128 ----
    {
        const int g128 = ((N_NODES + 1) * 128 + TB - 1) / TB;
        k_mm_fused<32, 128><<<g128, TB, 0, stream>>>(bufC, b2, bnp2, W3, dis, bufH);
        k_agg_v3<128><<<gridAgg, TB, 0, stream>>>(bufH, offs, csr, dis, bufC);
        k_stats<128><<<256, 256, 0, stream>>>(bufC, b3, stats3);
        k_bnprep<128><<<1, 128, 0, stream>>>(stats3, g3, be3, bnp3);
    }

    // pool (fused bn+relu) + head
    k_pool<<<N_GRAPHS, 128, 0, stream>>>(bufC, batch, b3, bnp3, pooled);
    k_head<<<(N_GRAPHS + TB - 1) / TB, TB, 0, stream>>>(pooled, Wl, bl, out);
}

// Round 4
// 772.742 us; speedup vs baseline: 2.1391x; 2.1391x over previous
//
#include <hip/hip_runtime.h>
#include <hip/hip_bf16.h>
#include <hip/hip_fp16.h>
#include <math.h>

#define N_NODES 100000
#define N_EDGES 3200000
#define N_GRAPHS 512
#define BN_EPS 1e-5f
#define NBIN ((N_NODES + 255) / 256)      // 391 bins of 256 nodes
#define CHUNK 8192                        // edges per partition block
#define NCHUNK ((N_EDGES + CHUNK - 1) / CHUNK)  // 391

// ---------------- CSR build: LDS-binned radix partition ----------------

__global__ void k_hist(const int* __restrict__ dst, int* __restrict__ ghist) {
    __shared__ int h[NBIN];
    for (int i = threadIdx.x; i < NBIN; i += blockDim.x) h[i] = 0;
    __syncthreads();
    int e0 = blockIdx.x * CHUNK;
    int e1 = min(e0 + CHUNK, N_EDGES);
    for (int e = e0 + threadIdx.x; e < e1; e += blockDim.x)
        atomicAdd(&h[dst[e] >> 8], 1);
    __syncthreads();
    for (int i = threadIdx.x; i < NBIN; i += blockDim.x)
        if (h[i]) atomicAdd(&ghist[i], h[i]);
}

__global__ void k_binscan(const int* __restrict__ ghist, int* __restrict__ bbase,
                          int* __restrict__ bcur, int* __restrict__ offs) {
    __shared__ int sd[512];
    int t = threadIdx.x;
    int v = (t < NBIN) ? ghist[t] : 0;
    sd[t] = v;
    __syncthreads();
    for (int off = 1; off < 512; off <<= 1) {
        int u = (t >= off) ? sd[t - off] : 0;
        __syncthreads();
        sd[t] += u;
        __syncthreads();
    }
    if (t < NBIN) { int ex = sd[t] - v; bbase[t] = ex; bcur[t] = ex; }
    if (t == 0) { bbase[NBIN] = N_EDGES; offs[N_NODES] = N_EDGES; }
}

// per-block: LDS hist -> one reservation atomic per bin -> run-contiguous scatter
__global__ void k_partition(const int* __restrict__ src, const int* __restrict__ dst,
                            int* __restrict__ bcur, int* __restrict__ store) {
    __shared__ int h[NBIN], gb[NBIN];
    for (int i = threadIdx.x; i < NBIN; i += blockDim.x) h[i] = 0;
    __syncthreads();
    int e0 = blockIdx.x * CHUNK;
    int e1 = min(e0 + CHUNK, N_EDGES);
    for (int e = e0 + threadIdx.x; e < e1; e += blockDim.x)
        atomicAdd(&h[dst[e] >> 8], 1);
    __syncthreads();
    for (int i = threadIdx.x; i < NBIN; i += blockDim.x) {
        int c = h[i];
        gb[i] = c ? atomicAdd(&bcur[i], c) : 0;
        h[i] = 0;   // reuse as local cursor
    }
    __syncthreads();
    for (int e = e0 + threadIdx.x; e < e1; e += blockDim.x) {
        int d = dst[e];
        int b = d >> 8;
        int r = atomicAdd(&h[b], 1);
        store[gb[b] + r] = (src[e] << 8) | (d & 255);  // src<2^17, fits 25 bits
    }
}

// one block per bin: counts/scan/scatter inside a ~32KB L2-resident window
__global__ void k_csr_build(const int* __restrict__ bbase, const int* __restrict__ store,
                            int* __restrict__ offs, float* __restrict__ dis,
                            int* __restrict__ csr) {
    __shared__ int cnt[256], cur[256], wsum[4];
    int b = blockIdx.x;
    int n0 = b << 8;
    int nn = min(256, N_NODES - n0);
    int e0 = bbase[b], e1 = bbase[b + 1];
    int t = threadIdx.x;
    cnt[t] = 0;
    __syncthreads();
    for (int e = e0 + t; e < e1; e += 256) atomicAdd(&cnt[store[e] & 255], 1);
    __syncthreads();
    int c = cnt[t];
    int inc = c;
    int lane = t & 63, wid = t >> 6;
#pragma unroll
    for (int off = 1; off < 64; off <<= 1) {
        int u = __shfl_up(inc, off, 64);
        if (lane >= off) inc += u;
    }
    if (lane == 63) wsum[wid] = inc;
    __syncthreads();
    int wo = 0;
    for (int w = 0; w < wid; ++w) wo += wsum[w];
    int ex = inc - c + wo;
    cur[t] = ex;
    if (t < nn) {
        offs[n0 + t] = e0 + ex;
        dis[n0 + t] = rsqrtf(1.0f + (float)c);
    }
    __syncthreads();
    for (int e = e0 + t; e < e1; e += 256) {
        int p = store[e];
        int pos = e0 + atomicAdd(&cur[p & 255], 1);
        csr[pos] = p >> 8;
    }
}

// ---------------- layer-1 matmul, fp16 out, dis-prescaled, zero row at N ----------------

template <int FIN, int FOUT>
__global__ void k_mm_h(const float* __restrict__ h, const float* __restrict__ W,
                       const float* __restrict__ dis, __half* __restrict__ out) {
    __shared__ float sW[FIN * FOUT];
    for (int i = threadIdx.x; i < FIN * FOUT; i += blockDim.x) sW[i] = W[i];
    __syncthreads();
    int gid = blockIdx.x * blockDim.x + threadIdx.x;
    if (gid >= (N_NODES + 1) * FOUT) return;
    int n = gid / FOUT, f = gid % FOUT;
    if (n == N_NODES) { out[gid] = __float2half(0.f); return; }
    float acc = 0.f;
#pragma unroll
    for (int i = 0; i < FIN; ++i) acc += h[n * FIN + i] * sW[i * FOUT + f];
    out[gid] = __float2half(acc * dis[n]);
}

// ---------------- fused bn(relu(conv+bias)) @ W matmul ----------------

template <int FIN, int FOUT>
__global__ void k_mm_fused(const float* __restrict__ conv, const float* __restrict__ bias,
                           const float* __restrict__ bnp, const float* __restrict__ W,
                           const float* __restrict__ dis, __half* __restrict__ out) {
    __shared__ float sW[FIN * FOUT];
    __shared__ float scb[FOUT];
    for (int i = threadIdx.x; i < FIN * FOUT; i += blockDim.x)
        sW[i] = bnp[i / FOUT] * W[i];
    if (threadIdx.x < FOUT) {
        float cb = 0.f;
#pragma unroll
        for (int r = 0; r < FIN; ++r) cb += bnp[FIN + r] * W[r * FOUT + threadIdx.x];
        scb[threadIdx.x] = cb;
    }
    __syncthreads();
    int gid = blockIdx.x * blockDim.x + threadIdx.x;
    if (gid >= (N_NODES + 1) * FOUT) return;
    int n = gid / FOUT, f = gid % FOUT;
    if (n == N_NODES) { out[gid] = __float2half(0.f); return; }
    float acc = scb[f];
#pragma unroll
    for (int i = 0; i < FIN; ++i) {
        float y = conv[n * FIN + i] + bias[i];
        y = y > 0.f ? y : 0.f;
        acc += y * sW[i * FOUT + f];
    }
    out[gid] = __float2half(acc * dis[n]);
}

// ---------------- GCN aggregation (wave-per-node, half4 gather, zero-row tails) ----------------

struct alignas(8) h4 { __half2 a, b; };

template <int FOUT>
__global__ void k_agg_v3(const __half* __restrict__ hWd, const int* __restrict__ offs,
                         const int* __restrict__ csr, const float* __restrict__ dis,
                         float* __restrict__ out) {
    constexpr int LPE = FOUT / 4;
    constexpr int EPI = 64 / LPE;
    int wave = threadIdx.x >> 6;
    int lane = threadIdx.x & 63;
    int node = blockIdx.x * (blockDim.x >> 6) + wave;
    if (node >= N_NODES) return;
    int chunk = lane % LPE;
    int eg    = lane / LPE;

    int e0 = offs[node], e1 = offs[node + 1];
    float dn = dis[node];
    float ax = 0.f, ay = 0.f, az = 0.f, aw = 0.f;
    const __half* hp = hWd + (size_t)chunk * 4;

    for (int e = e0 + eg; e < e1; e += 4 * EPI) {
        int s0 = csr[e];
        int s1 = (e + EPI     < e1) ? csr[e + EPI]     : N_NODES;
        int s2 = (e + 2 * EPI < e1) ? csr[e + 2 * EPI] : N_NODES;
        int s3 = (e + 3 * EPI < e1) ? csr[e + 3 * EPI] : N_NODES;
        h4 v0 = *(const h4*)(hp + (size_t)s0 * FOUT);
        h4 v1 = *(const h4*)(hp + (size_t)s1 * FOUT);
        h4 v2 = *(const h4*)(hp + (size_t)s2 * FOUT);
        h4 v3 = *(const h4*)(hp + (size_t)s3 * FOUT);
        ax += __low2float(v0.a) + __low2float(v1.a) + __low2float(v2.a) + __low2float(v3.a);
        ay += __high2float(v0.a) + __high2float(v1.a) + __high2float(v2.a) + __high2float(v3.a);
        az += __low2float(v0.b) + __low2float(v1.b) + __low2float(v2.b) + __low2float(v3.b);
        aw += __high2float(v0.b) + __high2float(v1.b) + __high2float(v2.b) + __high2float(v3.b);
    }
    if (eg == 0) {  // self-loop
        h4 v = *(const h4*)(hp + (size_t)node * FOUT);
        ax += __low2float(v.a);
        ay += __high2float(v.a);
        az += __low2float(v.b);
        aw += __high2float(v.b);
    }
#pragma unroll
    for (int off = LPE; off < 64; off <<= 1) {
        ax += __shfl_xor(ax, off, 64);
        ay += __shfl_xor(ay, off, 64);
        az += __shfl_xor(az, off, 64);
        aw += __shfl_xor(aw, off, 64);
    }
    if (lane < LPE) {
        float4 r = make_float4(dn * ax, dn * ay, dn * az, dn * aw);
        *(float4*)(out + (size_t)node * FOUT + chunk * 4) = r;
    }
}

// ---------------- BN stats over y = relu(conv + bias) ----------------

template <int FOUT>
__global__ void k_stats(const float* __restrict__ conv, const float* __restrict__ bias,
                        float* __restrict__ stats) {
    constexpr int GP = 256 / FOUT;
    int f = threadIdx.x % FOUT, g = threadIdx.x / FOUT;
    float bf = bias[f];
    float s = 0.f, s2 = 0.f;
    for (int n = blockIdx.x * GP + g; n < N_NODES; n += gridDim.x * GP) {
        float y = conv[n * FOUT + f] + bf;
        y = y > 0.f ? y : 0.f;
        s += y;
        s2 += y * y;
    }
    __shared__ float ls[256], ls2[256];
    ls[threadIdx.x] = s;
    ls2[threadIdx.x] = s2;
    __syncthreads();
    if (g == 0) {
        for (int gg = 1; gg < GP; ++gg) {
            s += ls[gg * FOUT + f];
            s2 += ls2[gg * FOUT + f];
        }
        atomicAdd(&stats[f], s);
        atomicAdd(&stats[FOUT + f], s2);
    }
}

template <int FOUT>
__global__ void k_bnprep(const float* __restrict__ stats, const float* __restrict__ gamma,
                         const float* __restrict__ beta, float* __restrict__ bnp) {
    int f = threadIdx.x;
    if (f >= FOUT) return;
    float inv_n = 1.0f / (float)N_NODES;
    float m = stats[f] * inv_n;
    float v = stats[FOUT + f] * inv_n - m * m;
    float a = gamma[f] * rsqrtf(v + BN_EPS);
    bnp[f] = a;
    bnp[FOUT + f] = beta[f] - m * a;
}

// ---------------- pool with fused bn(relu(conv+b)) + head ----------------

__device__ __forceinline__ int lower_bound_dev(const int* __restrict__ a, int val) {
    int lo = 0, hi = N_NODES;
    while (lo < hi) {
        int mid = (lo + hi) >> 1;
        if (a[mid] < val) lo = mid + 1; else hi = mid;
    }
    return lo;
}

__global__ void k_pool(const float* __restrict__ conv, const int* __restrict__ batch,
                       const float* __restrict__ bias, const float* __restrict__ bnp,
                       float* __restrict__ pooled) {
    int g = blockIdx.x;
    int f = threadIdx.x;
    int s = lower_bound_dev(batch, g);
    int e = lower_bound_dev(batch, g + 1);
    float bf = bias[f];
    float mx = -INFINITY, mn = INFINITY;
    for (int n = s; n < e; ++n) {
        float y = conv[n * 128 + f] + bf;
        y = y > 0.f ? y : 0.f;
        mx = fmaxf(mx, y);
        mn = fminf(mn, y);
    }
    float a = bnp[f], c = bnp[128 + f];
    float r;
    if (e > s) r = (a >= 0.f) ? (a * mx + c) : (a * mn + c);
    else r = -INFINITY;
    pooled[g * 128 + f] = r;
}

__global__ void k_head(const float* __restrict__ pooled, const float* __restrict__ Wl,
                       const float* __restrict__ bl, float* __restrict__ out) {
    int g = blockIdx.x * blockDim.x + threadIdx.x;
    if (g >= N_GRAPHS) return;
    float l0 = bl[0], l1 = bl[1], l2 = bl[2];
    for (int i = 0; i < 128; ++i) {
        float p = pooled[g * 128 + i];
        l0 += p * Wl[i * 3 + 0];
        l1 += p * Wl[i * 3 + 1];
        l2 += p * Wl[i * 3 + 2];
    }
    float mx = fmaxf(l0, fmaxf(l1, l2));
    float lse = mx + logf(expf(l0 - mx) + expf(l1 - mx) + expf(l2 - mx));
    out[g * 3 + 0] = l0 - lse;
    out[g * 3 + 1] = l1 - lse;
    out[g * 3 + 2] = l2 - lse;
}

// ---------------- launch ----------------

extern "C" void kernel_launch(void* const* d_in, const int* in_sizes, int n_in,
                              void* d_out, int out_size, void* d_ws, size_t ws_size,
                              hipStream_t stream) {
    const float* x   = (const float*)d_in[0];
    const int* ei    = (const int*)d_in[1];
    const int* src   = ei;
    const int* dst   = ei + N_EDGES;
    const int* batch = (const int*)d_in[2];
    const float *W1 = (const float*)d_in[3],  *b1 = (const float*)d_in[4];
    const float *g1 = (const float*)d_in[5],  *be1 = (const float*)d_in[6];
    const float *W2 = (const float*)d_in[7],  *b2 = (const float*)d_in[8];
    const float *g2 = (const float*)d_in[9],  *be2 = (const float*)d_in[10];
    const float *W3 = (const float*)d_in[11], *b3 = (const float*)d_in[12];
    const float *g3 = (const float*)d_in[13], *be3 = (const float*)d_in[14];
    const float *Wl = (const float*)d_in[15], *bl = (const float*)d_in[16];
    float* out = (float*)d_out;

    // workspace carve (4-byte units). zeroed block first.
    int* base = (int*)d_ws;
    size_t o = 0;
    int* ghist    = base + o; o += NBIN;
    float* stats1 = (float*)(base + o); o += 256;
    float* stats2 = (float*)(base + o); o += 256;
    float* stats3 = (float*)(base + o); o += 256;
    size_t zero_words = o;
    int* bbase   = base + o; o += NBIN + 1;
    int* bcur    = base + o; o += NBIN;
    float* bnp1  = (float*)(base + o); o += 256;
    float* bnp2  = (float*)(base + o); o += 256;
    float* bnp3  = (float*)(base + o); o += 256;
    int* offs    = base + o; o += N_NODES + 1;
    int* store   = base + o; o += N_EDGES;
    int* csr     = base + o; o += N_EDGES;
    float* dis   = (float*)(base + o); o += N_NODES;
    float* pooled= (float*)(base + o); o += (size_t)N_GRAPHS * 128;
    __half* bufH = (__half*)(base + o); o += (size_t)(N_NODES + 1) * 64;
    float* bufC  = (float*)(base + o); o += (size_t)N_NODES * 128;
    if (ws_size < o * 4) return;

    const int TB = 256;
    const int gridAgg = (N_NODES + 3) / 4;

    hipMemsetAsync(base, 0, zero_words * 4, stream);

    // CSR build (LDS-binned radix partition)
    k_hist<<<NCHUNK, TB, 0, stream>>>(dst, ghist);
    k_binscan<<<1, 512, 0, stream>>>(ghist, bbase, bcur, offs);
    k_partition<<<NCHUNK, TB, 0, stream>>>(src, dst, bcur, store);
    k_csr_build<<<NBIN, 256, 0, stream>>>(bbase, store, offs, dis, csr);

    // ---- layer 1: 2 -> 8 ----
    {
        const int g8 = ((N_NODES + 1) * 8 + TB - 1) / TB;
        k_mm_h<2, 8><<<g8, TB, 0, stream>>>(x, W1, dis, bufH);
        k_agg_v3<8><<<gridAgg, TB, 0, stream>>>(bufH, offs, csr, dis, bufC);
        k_stats<8><<<256, 256, 0, stream>>>(bufC, b1, stats1);
        k_bnprep<8><<<1, 8, 0, stream>>>(stats1, g1, be1, bnp1);
    }
    // ---- layer 2: 8 -> 32 ----
    {
        const int g32 = ((N_NODES + 1) * 32 + TB - 1) / TB;
        k_mm_fused<8, 32><<<g32, TB, 0, stream>>>(bufC, b1, bnp1, W2, dis, bufH);
        k_agg_v3<32><<<gridAgg, TB, 0, stream>>>(bufH, offs, csr, dis, bufC);
        k_stats<32><<<256, 256, 0, stream>>>(bufC, b2, stats2);
        k_bnprep<32><<<1, 32, 0, stream>>>(stats2, g2, be2, bnp2);
    }
    // ---- layer 3: 32 -> 128 ----
    {
        const int g128 = ((N_NODES + 1) * 128 + TB - 1) / TB;
        k_mm_fused<32, 128><<<g128, TB, 0, stream>>>(bufC, b2, bnp2, W3, dis, bufH);
        k_agg_v3<128><<<gridAgg, TB, 0, stream>>>(bufH, offs, csr, dis, bufC);
        k_stats<128><<<256, 256, 0, stream>>>(bufC, b3, stats3);
        k_bnprep<128><<<1, 128, 0, stream>>>(stats3, g3, be3, bnp3);
    }

    // pool (fused bn+relu) + head
    k_pool<<<N_GRAPHS, 128, 0, stream>>>(bufC, batch, b3, bnp3, pooled);
    k_head<<<(N_GRAPHS + TB - 1) / TB, TB, 0, stream>>>(pooled, Wl, bl, out);
}

// Round 5
// 629.538 us; speedup vs baseline: 2.6257x; 1.2275x over previous
//
#include <hip/hip_runtime.h>
#include <hip/hip_bf16.h>
#include <hip/hip_fp16.h>
#include <math.h>

#define N_NODES 100000
#define N_EDGES 3200000
#define N_GRAPHS 512
#define BN_EPS 1e-5f
#define NBIN ((N_NODES + 255) / 256)      // 391 bins of 256 nodes
#define CHUNK 8192                        // edges per partition block
#define NCHUNK ((N_EDGES + CHUNK - 1) / CHUNK)  // 391

typedef _Float16 half8_t __attribute__((ext_vector_type(8)));
typedef float float4_t __attribute__((ext_vector_type(4)));

// ---------------- CSR build: LDS-binned radix partition ----------------

__global__ void k_hist(const int* __restrict__ dst, int* __restrict__ ghist) {
    __shared__ int h[NBIN];
    for (int i = threadIdx.x; i < NBIN; i += blockDim.x) h[i] = 0;
    __syncthreads();
    int e0 = blockIdx.x * CHUNK;
    int e1 = min(e0 + CHUNK, N_EDGES);
    for (int e = e0 + threadIdx.x; e < e1; e += blockDim.x)
        atomicAdd(&h[dst[e] >> 8], 1);
    __syncthreads();
    for (int i = threadIdx.x; i < NBIN; i += blockDim.x)
        if (h[i]) atomicAdd(&ghist[i], h[i]);
}

__global__ void k_binscan(const int* __restrict__ ghist, int* __restrict__ bbase,
                          int* __restrict__ bcur, int* __restrict__ offs) {
    __shared__ int sd[512];
    int t = threadIdx.x;
    int v = (t < NBIN) ? ghist[t] : 0;
    sd[t] = v;
    __syncthreads();
    for (int off = 1; off < 512; off <<= 1) {
        int u = (t >= off) ? sd[t - off] : 0;
        __syncthreads();
        sd[t] += u;
        __syncthreads();
    }
    if (t < NBIN) { int ex = sd[t] - v; bbase[t] = ex; bcur[t] = ex; }
    if (t == 0) { bbase[NBIN] = N_EDGES; offs[N_NODES] = N_EDGES; }
}

__global__ void k_partition(const int* __restrict__ src, const int* __restrict__ dst,
                            int* __restrict__ bcur, int* __restrict__ store) {
    __shared__ int h[NBIN], gb[NBIN];
    for (int i = threadIdx.x; i < NBIN; i += blockDim.x) h[i] = 0;
    __syncthreads();
    int e0 = blockIdx.x * CHUNK;
    int e1 = min(e0 + CHUNK, N_EDGES);
    for (int e = e0 + threadIdx.x; e < e1; e += blockDim.x)
        atomicAdd(&h[dst[e] >> 8], 1);
    __syncthreads();
    for (int i = threadIdx.x; i < NBIN; i += blockDim.x) {
        int c = h[i];
        gb[i] = c ? atomicAdd(&bcur[i], c) : 0;
        h[i] = 0;   // reuse as local cursor
    }
    __syncthreads();
    for (int e = e0 + threadIdx.x; e < e1; e += blockDim.x) {
        int d = dst[e];
        int b = d >> 8;
        int r = atomicAdd(&h[b], 1);
        store[gb[b] + r] = (src[e] << 8) | (d & 255);
    }
}

__global__ void k_csr_build(const int* __restrict__ bbase, const int* __restrict__ store,
                            int* __restrict__ offs, float* __restrict__ dis,
                            int* __restrict__ csr) {
    __shared__ int cnt[256], cur[256], wsum[4];
    int b = blockIdx.x;
    int n0 = b << 8;
    int nn = min(256, N_NODES - n0);
    int e0 = bbase[b], e1 = bbase[b + 1];
    int t = threadIdx.x;
    cnt[t] = 0;
    __syncthreads();
    for (int e = e0 + t; e < e1; e += 256) atomicAdd(&cnt[store[e] & 255], 1);
    __syncthreads();
    int c = cnt[t];
    int inc = c;
    int lane = t & 63, wid = t >> 6;
#pragma unroll
    for (int off = 1; off < 64; off <<= 1) {
        int u = __shfl_up(inc, off, 64);
        if (lane >= off) inc += u;
    }
    if (lane == 63) wsum[wid] = inc;
    __syncthreads();
    int wo = 0;
    for (int w = 0; w < wid; ++w) wo += wsum[w];
    int ex = inc - c + wo;
    cur[t] = ex;
    if (t < nn) {
        offs[n0 + t] = e0 + ex;
        dis[n0 + t] = rsqrtf(1.0f + (float)c);
    }
    __syncthreads();
    for (int e = e0 + t; e < e1; e += 256) {
        int p = store[e];
        int pos = e0 + atomicAdd(&cur[p & 255], 1);
        csr[pos] = p >> 8;
    }
}

// ---------------- layer-1 matmul, fp16 out, dis-prescaled, zero row at N ----------------

template <int FIN, int FOUT>
__global__ void k_mm_h(const float* __restrict__ h, const float* __restrict__ W,
                       const float* __restrict__ dis, __half* __restrict__ out) {
    __shared__ float sW[FIN * FOUT];
    for (int i = threadIdx.x; i < FIN * FOUT; i += blockDim.x) sW[i] = W[i];
    __syncthreads();
    int gid = blockIdx.x * blockDim.x + threadIdx.x;
    if (gid >= (N_NODES + 1) * FOUT) return;
    int n = gid / FOUT, f = gid % FOUT;
    if (n == N_NODES) { out[gid] = __float2half(0.f); return; }
    float acc = 0.f;
#pragma unroll
    for (int i = 0; i < FIN; ++i) acc += h[n * FIN + i] * sW[i * FOUT + f];
    out[gid] = __float2half(acc * dis[n]);
}

// ---------------- fused bn(relu(conv+bias)) @ W matmul (scalar; layer 2 only) ----------------

template <int FIN, int FOUT>
__global__ void k_mm_fused(const float* __restrict__ conv, const float* __restrict__ bias,
                           const float* __restrict__ bnp, const float* __restrict__ W,
                           const float* __restrict__ dis, __half* __restrict__ out) {
    __shared__ float sW[FIN * FOUT];
    __shared__ float scb[FOUT];
    for (int i = threadIdx.x; i < FIN * FOUT; i += blockDim.x)
        sW[i] = bnp[i / FOUT] * W[i];
    if (threadIdx.x < FOUT) {
        float cb = 0.f;
#pragma unroll
        for (int r = 0; r < FIN; ++r) cb += bnp[FIN + r] * W[r * FOUT + threadIdx.x];
        scb[threadIdx.x] = cb;
    }
    __syncthreads();
    int gid = blockIdx.x * blockDim.x + threadIdx.x;
    if (gid >= (N_NODES + 1) * FOUT) return;
    int n = gid / FOUT, f = gid % FOUT;
    if (n == N_NODES) { out[gid] = __float2half(0.f); return; }
    float acc = scb[f];
#pragma unroll
    for (int i = 0; i < FIN; ++i) {
        float y = conv[n * FIN + i] + bias[i];
        y = y > 0.f ? y : 0.f;
        acc += y * sW[i * FOUT + f];
    }
    out[gid] = __float2half(acc * dis[n]);
}

// ---------------- layer-3 MFMA matmul prep ----------------
// wfrag[(g*4+kq)*16+c][j] = bnp[k]*W[k][g*16+c] (fp16), k = kq*8+j
// wcb[c] = sum_k bnp[32+k]*W[k][c]
// also writes the zero row of bufH (row N_NODES)

__global__ void k_prepW(const float* __restrict__ bnp, const float* __restrict__ W,
                        __half* __restrict__ wfrag, float* __restrict__ wcb,
                        __half* __restrict__ bufH) {
    int t = threadIdx.x;   // 512 threads
    {   // fragment table: slot t, 8 entries
        int g = t >> 6, kq = (t >> 4) & 3, c = t & 15;
#pragma unroll
        for (int j = 0; j < 8; ++j) {
            int k = kq * 8 + j;
            wfrag[(size_t)t * 8 + j] = __float2half(bnp[k] * W[k * 128 + g * 16 + c]);
        }
    }
    if (t < 128) {
        float cb = 0.f;
#pragma unroll
        for (int k = 0; k < 32; ++k) cb += bnp[32 + k] * W[k * 128 + t];
        wcb[t] = cb;
    }
    if (t >= 128 && t < 160) {  // zero row for agg tails
        int q = t - 128;
        ((__half2*)(bufH + (size_t)N_NODES * 128))[q * 2]     = __half2{__float2half(0.f), __float2half(0.f)};
        ((__half2*)(bufH + (size_t)N_NODES * 128))[q * 2 + 1] = __half2{__float2half(0.f), __float2half(0.f)};
    }
}

// ---------------- layer-3 matmul via MFMA 16x16x32 f16 ----------------
// out[n] = dis[n] * ( relu(conv[n]+bias) @ (diag(a)W) + c@W ), fp16

__global__ void k_mm_mfma(const float* __restrict__ conv, const float* __restrict__ bias,
                          const __half* __restrict__ wfrag, const float* __restrict__ wcb,
                          const float* __restrict__ dis, __half* __restrict__ out) {
    int wave = threadIdx.x >> 6;
    int lane = threadIdx.x & 63;
    int n0 = (blockIdx.x * 4 + wave) * 16;      // 16 nodes per wave
    if (n0 >= N_NODES) return;
    int m = lane & 15;      // node-row within tile (A) / col within group (B,D)
    int kq = lane >> 4;     // k-quad

    int n = n0 + m;
    float4 c0 = *(const float4*)(conv + (size_t)n * 32 + kq * 8);
    float4 c1 = *(const float4*)(conv + (size_t)n * 32 + kq * 8 + 4);
    float4 b0 = *(const float4*)(bias + kq * 8);
    float4 b1 = *(const float4*)(bias + kq * 8 + 4);
    half8_t af;
    af[0] = (_Float16)fmaxf(c0.x + b0.x, 0.f);
    af[1] = (_Float16)fmaxf(c0.y + b0.y, 0.f);
    af[2] = (_Float16)fmaxf(c0.z + b0.z, 0.f);
    af[3] = (_Float16)fmaxf(c0.w + b0.w, 0.f);
    af[4] = (_Float16)fmaxf(c1.x + b1.x, 0.f);
    af[5] = (_Float16)fmaxf(c1.y + b1.y, 0.f);
    af[6] = (_Float16)fmaxf(c1.z + b1.z, 0.f);
    af[7] = (_Float16)fmaxf(c1.w + b1.w, 0.f);

    float4_t accs[8];
#pragma unroll
    for (int g = 0; g < 8; ++g) {
        float cb = wcb[g * 16 + m];
        float4_t acc = {cb, cb, cb, cb};
        half8_t bf = *(const half8_t*)(wfrag + (size_t)((g * 4 + kq) * 16 + m) * 8);
        accs[g] = __builtin_amdgcn_mfma_f32_16x16x32_f16(af, bf, acc, 0, 0, 0);
    }
    float dnv[4];
#pragma unroll
    for (int r = 0; r < 4; ++r) dnv[r] = dis[n0 + kq * 4 + r];
#pragma unroll
    for (int g = 0; g < 8; ++g)
#pragma unroll
        for (int r = 0; r < 4; ++r)
            out[(size_t)(n0 + kq * 4 + r) * 128 + g * 16 + m] =
                __float2half(accs[g][r] * dnv[r]);
}

// ---------------- GCN aggregation (wave-per-node, half4 gather, zero-row tails) ----------------

struct alignas(8) h4 { __half2 a, b; };

template <int FOUT, int UNROLL>
__global__ void k_agg_v4(const __half* __restrict__ hWd, const int* __restrict__ offs,
                         const int* __restrict__ csr, const float* __restrict__ dis,
                         float* __restrict__ out) {
    constexpr int LPE = FOUT / 4;
    constexpr int EPI = 64 / LPE;
    int wave = threadIdx.x >> 6;
    int lane = threadIdx.x & 63;
    int node = blockIdx.x * (blockDim.x >> 6) + wave;
    if (node >= N_NODES) return;
    int chunk = lane % LPE;
    int eg    = lane / LPE;

    int e0 = offs[node], e1 = offs[node + 1];
    float dn = dis[node];
    float ax = 0.f, ay = 0.f, az = 0.f, aw = 0.f;
    const __half* hp = hWd + (size_t)chunk * 4;

    for (int e = e0 + eg; e < e1; e += UNROLL * EPI) {
        int s[UNROLL];
        s[0] = csr[e];
#pragma unroll
        for (int u = 1; u < UNROLL; ++u)
            s[u] = (e + u * EPI < e1) ? csr[e + u * EPI] : N_NODES;
        h4 v[UNROLL];
#pragma unroll
        for (int u = 0; u < UNROLL; ++u)
            v[u] = *(const h4*)(hp + (size_t)s[u] * FOUT);
#pragma unroll
        for (int u = 0; u < UNROLL; ++u) {
            ax += __low2float(v[u].a);
            ay += __high2float(v[u].a);
            az += __low2float(v[u].b);
            aw += __high2float(v[u].b);
        }
    }
    if (eg == 0) {  // self-loop
        h4 v = *(const h4*)(hp + (size_t)node * FOUT);
        ax += __low2float(v.a);
        ay += __high2float(v.a);
        az += __low2float(v.b);
        aw += __high2float(v.b);
    }
#pragma unroll
    for (int off = LPE; off < 64; off <<= 1) {
        ax += __shfl_xor(ax, off, 64);
        ay += __shfl_xor(ay, off, 64);
        az += __shfl_xor(az, off, 64);
        aw += __shfl_xor(aw, off, 64);
    }
    if (lane < LPE) {
        float4 r = make_float4(dn * ax, dn * ay, dn * az, dn * aw);
        *(float4*)(out + (size_t)node * FOUT + chunk * 4) = r;
    }
}

// ---------------- BN stats over y = relu(conv + bias) ----------------

template <int FOUT>
__global__ void k_stats(const float* __restrict__ conv, const float* __restrict__ bias,
                        float* __restrict__ stats) {
    constexpr int GP = 256 / FOUT;
    int f = threadIdx.x % FOUT, g = threadIdx.x / FOUT;
    float bf = bias[f];
    float s = 0.f, s2 = 0.f;
    for (int n = blockIdx.x * GP + g; n < N_NODES; n += gridDim.x * GP) {
        float y = conv[n * FOUT + f] + bf;
        y = y > 0.f ? y : 0.f;
        s += y;
        s2 += y * y;
    }
    __shared__ float ls[256], ls2[256];
    ls[threadIdx.x] = s;
    ls2[threadIdx.x] = s2;
    __syncthreads();
    if (g == 0) {
        for (int gg = 1; gg < GP; ++gg) {
            s += ls[gg * FOUT + f];
            s2 += ls2[gg * FOUT + f];
        }
        atomicAdd(&stats[f], s);
        atomicAdd(&stats[FOUT + f], s2);
    }
}

template <int FOUT>
__global__ void k_bnprep(const float* __restrict__ stats, const float* __restrict__ gamma,
                         const float* __restrict__ beta, float* __restrict__ bnp) {
    int f = threadIdx.x;
    if (f >= FOUT) return;
    float inv_n = 1.0f / (float)N_NODES;
    float m = stats[f] * inv_n;
    float v = stats[FOUT + f] * inv_n - m * m;
    float a = gamma[f] * rsqrtf(v + BN_EPS);
    bnp[f] = a;
    bnp[FOUT + f] = beta[f] - m * a;
}

// ---------------- pool with fused bn(relu(conv+b)) + head ----------------

__device__ __forceinline__ int lower_bound_dev(const int* __restrict__ a, int val) {
    int lo = 0, hi = N_NODES;
    while (lo < hi) {
        int mid = (lo + hi) >> 1;
        if (a[mid] < val) lo = mid + 1; else hi = mid;
    }
    return lo;
}

__global__ void k_pool(const float* __restrict__ conv, const int* __restrict__ batch,
                       const float* __restrict__ bias, const float* __restrict__ bnp,
                       float* __restrict__ pooled) {
    int g = blockIdx.x;
    int f = threadIdx.x;
    int s = lower_bound_dev(batch, g);
    int e = lower_bound_dev(batch, g + 1);
    float bf = bias[f];
    float mx = -INFINITY, mn = INFINITY;
    for (int n = s; n < e; ++n) {
        float y = conv[n * 128 + f] + bf;
        y = y > 0.f ? y : 0.f;
        mx = fmaxf(mx, y);
        mn = fminf(mn, y);
    }
    float a = bnp[f], c = bnp[128 + f];
    float r;
    if (e > s) r = (a >= 0.f) ? (a * mx + c) : (a * mn + c);
    else r = -INFINITY;
    pooled[g * 128 + f] = r;
}

__global__ void k_head(const float* __restrict__ pooled, const float* __restrict__ Wl,
                       const float* __restrict__ bl, float* __restrict__ out) {
    int g = blockIdx.x * blockDim.x + threadIdx.x;
    if (g >= N_GRAPHS) return;
    float l0 = bl[0], l1 = bl[1], l2 = bl[2];
    for (int i = 0; i < 128; ++i) {
        float p = pooled[g * 128 + i];
        l0 += p * Wl[i * 3 + 0];
        l1 += p * Wl[i * 3 + 1];
        l2 += p * Wl[i * 3 + 2];
    }
    float mx = fmaxf(l0, fmaxf(l1, l2));
    float lse = mx + logf(expf(l0 - mx) + expf(l1 - mx) + expf(l2 - mx));
    out[g * 3 + 0] = l0 - lse;
    out[g * 3 + 1] = l1 - lse;
    out[g * 3 + 2] = l2 - lse;
}

// ---------------- launch ----------------

extern "C" void kernel_launch(void* const* d_in, const int* in_sizes, int n_in,
                              void* d_out, int out_size, void* d_ws, size_t ws_size,
                              hipStream_t stream) {
    const float* x   = (const float*)d_in[0];
    const int* ei    = (const int*)d_in[1];
    const int* src   = ei;
    const int* dst   = ei + N_EDGES;
    const int* batch = (const int*)d_in[2];
    const float *W1 = (const float*)d_in[3],  *b1 = (const float*)d_in[4];
    const float *g1 = (const float*)d_in[5],  *be1 = (const float*)d_in[6];
    const float *W2 = (const float*)d_in[7],  *b2 = (const float*)d_in[8];
    const float *g2 = (const float*)d_in[9],  *be2 = (const float*)d_in[10];
    const float *W3 = (const float*)d_in[11], *b3 = (const float*)d_in[12];
    const float *g3 = (const float*)d_in[13], *be3 = (const float*)d_in[14];
    const float *Wl = (const float*)d_in[15], *bl = (const float*)d_in[16];
    float* out = (float*)d_out;

    // workspace carve (4-byte units). zeroed block first.
    int* base = (int*)d_ws;
    size_t o = 0;
    int* ghist    = base + o; o += NBIN;
    float* stats1 = (float*)(base + o); o += 256;
    float* stats2 = (float*)(base + o); o += 256;
    float* stats3 = (float*)(base + o); o += 256;
    size_t zero_words = o;
    int* bbase   = base + o; o += NBIN + 1;
    int* bcur    = base + o; o += NBIN;
    float* bnp1  = (float*)(base + o); o += 256;
    float* bnp2  = (float*)(base + o); o += 256;
    float* bnp3  = (float*)(base + o); o += 256;
    __half* wfrag = (__half*)(base + o); o += 2048;   // 4096 halfs
    float* wcb   = (float*)(base + o); o += 128;
    int* offs    = base + o; o += N_NODES + 1;
    int* store   = base + o; o += N_EDGES;
    int* csr     = base + o; o += N_EDGES;
    float* dis   = (float*)(base + o); o += N_NODES;
    float* pooled= (float*)(base + o); o += (size_t)N_GRAPHS * 128;
    __half* bufH = (__half*)(base + o); o += (size_t)(N_NODES + 1) * 64;
    float* bufC  = (float*)(base + o); o += (size_t)N_NODES * 128;
    if (ws_size < o * 4) return;

    const int TB = 256;
    const int gridAgg = (N_NODES + 3) / 4;

    hipMemsetAsync(base, 0, zero_words * 4, stream);

    // CSR build (LDS-binned radix partition)
    k_hist<<<NCHUNK, TB, 0, stream>>>(dst, ghist);
    k_binscan<<<1, 512, 0, stream>>>(ghist, bbase, bcur, offs);
    k_partition<<<NCHUNK, TB, 0, stream>>>(src, dst, bcur, store);
    k_csr_build<<<NBIN, 256, 0, stream>>>(bbase, store, offs, dis, csr);

    // ---- layer 1: 2 -> 8 ----
    {
        const int g8 = ((N_NODES + 1) * 8 + TB - 1) / TB;
        k_mm_h<2, 8><<<g8, TB, 0, stream>>>(x, W1, dis, bufH);
        k_agg_v4<8, 4><<<gridAgg, TB, 0, stream>>>(bufH, offs, csr, dis, bufC);
        k_stats<8><<<256, 256, 0, stream>>>(bufC, b1, stats1);
        k_bnprep<8><<<1, 8, 0, stream>>>(stats1, g1, be1, bnp1);
    }
    // ---- layer 2: 8 -> 32 ----
    {
        const int g32 = ((N_NODES + 1) * 32 + TB - 1) / TB;
        k_mm_fused<8, 32><<<g32, TB, 0, stream>>>(bufC, b1, bnp1, W2, dis, bufH);
        k_agg_v4<32, 4><<<gridAgg, TB, 0, stream>>>(bufH, offs, csr, dis, bufC);
        k_stats<32><<<256, 256, 0, stream>>>(bufC, b2, stats2);
        k_bnprep<32><<<1, 32, 0, stream>>>(stats2, g2, be2, bnp2);
    }
    // ---- layer 3: 32 -> 128 (MFMA) ----
    {
        k_prepW<<<1, 512, 0, stream>>>(bnp2, W3, wfrag, wcb, bufH);
        k_mm_mfma<<<(N_NODES + 63) / 64, 256, 0, stream>>>(bufC, b2, wfrag, wcb, dis, bufH);
        k_agg_v4<128, 8><<<gridAgg, TB, 0, stream>>>(bufH, offs, csr, dis, bufC);
        k_stats<128><<<256, 256, 0, stream>>>(bufC, b3, stats3);
        k_bnprep<128><<<1, 128, 0, stream>>>(stats3, g3, be3, bnp3);
    }

    // pool (fused bn+relu) + head
    k_pool<<<N_GRAPHS, 128, 0, stream>>>(bufC, batch, b3, bnp3, pooled);
    k_head<<<(N_GRAPHS + TB - 1) / TB, TB, 0, stream>>>(pooled, Wl, bl, out);
}

// Round 6
// 606.955 us; speedup vs baseline: 2.7234x; 1.0372x over previous
//
#include <hip/hip_runtime.h>
#include <hip/hip_bf16.h>
#include <hip/hip_fp16.h>
#include <math.h>

#define N_NODES 100000
#define N_EDGES 3200000
#define N_GRAPHS 512
#define BN_EPS 1e-5f
#define NBIN ((N_NODES + 255) / 256)            // 391 bins of 256 nodes
#define CHUNK 8192                              // edges per chunk block
#define NCHUNK ((N_EDGES + CHUNK - 1) / CHUNK)  // 391

typedef _Float16 half8_t __attribute__((ext_vector_type(8)));
typedef float float4_t __attribute__((ext_vector_type(4)));

// ---------------- CSR build: single-scatter radix ----------------
// pass 1: per-chunk histogram -> hists[bin * NCHUNK + chunk]
__global__ void k_hist2(const int* __restrict__ dst, int* __restrict__ hists) {
    __shared__ int h[NBIN];
    for (int i = threadIdx.x; i < NBIN; i += blockDim.x) h[i] = 0;
    __syncthreads();
    int e0 = blockIdx.x * CHUNK;
    int e1 = min(e0 + CHUNK, N_EDGES);
    for (int e = e0 + threadIdx.x; e < e1; e += blockDim.x)
        atomicAdd(&h[dst[e] >> 8], 1);
    __syncthreads();
    for (int i = threadIdx.x; i < NBIN; i += blockDim.x)
        hists[i * NCHUNK + blockIdx.x] = h[i];
}

// pass 2: per-bin exclusive scan over chunks (in place); totals -> ghist
__global__ void k_scan2(int* __restrict__ hists, int* __restrict__ ghist) {
    int b = blockIdx.x;
    int lane = threadIdx.x;   // 64 threads
    int carry = 0;
    int base = b * NCHUNK;
    for (int c0 = 0; c0 < NCHUNK; c0 += 64) {
        int c = c0 + lane;
        int v = (c < NCHUNK) ? hists[base + c] : 0;
        int inc = v;
#pragma unroll
        for (int off = 1; off < 64; off <<= 1) {
            int u = __shfl_up(inc, off, 64);
            if (lane >= off) inc += u;
        }
        if (c < NCHUNK) hists[base + c] = inc - v + carry;
        carry += __shfl(inc, 63, 64);
    }
    if (lane == 0) ghist[b] = carry;
}

// pass 3: scan bin totals -> bbase
__global__ void k_binscan(const int* __restrict__ ghist, int* __restrict__ bbase,
                          int* __restrict__ offs) {
    __shared__ int sd[512];
    int t = threadIdx.x;
    int v = (t < NBIN) ? ghist[t] : 0;
    sd[t] = v;
    __syncthreads();
    for (int off = 1; off < 512; off <<= 1) {
        int u = (t >= off) ? sd[t - off] : 0;
        __syncthreads();
        sd[t] += u;
        __syncthreads();
    }
    if (t < NBIN) bbase[t] = sd[t] - v;
    if (t == 0) { bbase[NBIN] = N_EDGES; offs[N_NODES] = N_EDGES; }
}

// pass 4: single-pass scatter with exact per-(chunk,bin) bases
__global__ void k_scatter(const int* __restrict__ src, const int* __restrict__ dst,
                          const int* __restrict__ bbase, const int* __restrict__ hists,
                          int* __restrict__ store) {
    __shared__ int cur[NBIN];
    for (int i = threadIdx.x; i < NBIN; i += blockDim.x)
        cur[i] = bbase[i] + hists[i * NCHUNK + blockIdx.x];
    __syncthreads();
    int e0 = blockIdx.x * CHUNK;
    int e1 = min(e0 + CHUNK, N_EDGES);
    for (int e = e0 + threadIdx.x; e < e1; e += blockDim.x) {
        int d = dst[e];
        int b = d >> 8;
        int pos = atomicAdd(&cur[b], 1);
        store[pos] = (src[e] << 8) | (d & 255);
    }
}

// pass 5: one block per bin -> offs, dis, csr (L2-resident window)
__global__ void k_csr_build(const int* __restrict__ bbase, const int* __restrict__ store,
                            int* __restrict__ offs, float* __restrict__ dis,
                            int* __restrict__ csr) {
    __shared__ int cnt[256], cur[256], wsum[4];
    int b = blockIdx.x;
    int n0 = b << 8;
    int nn = min(256, N_NODES - n0);
    int e0 = bbase[b], e1 = bbase[b + 1];
    int t = threadIdx.x;
    cnt[t] = 0;
    __syncthreads();
    for (int e = e0 + t; e < e1; e += 256) atomicAdd(&cnt[store[e] & 255], 1);
    __syncthreads();
    int c = cnt[t];
    int inc = c;
    int lane = t & 63, wid = t >> 6;
#pragma unroll
    for (int off = 1; off < 64; off <<= 1) {
        int u = __shfl_up(inc, off, 64);
        if (lane >= off) inc += u;
    }
    if (lane == 63) wsum[wid] = inc;
    __syncthreads();
    int wo = 0;
    for (int w = 0; w < wid; ++w) wo += wsum[w];
    int ex = inc - c + wo;
    cur[t] = ex;
    if (t < nn) {
        offs[n0 + t] = e0 + ex;
        dis[n0 + t] = rsqrtf(1.0f + (float)c);
    }
    __syncthreads();
    for (int e = e0 + t; e < e1; e += 256) {
        int p = store[e];
        int pos = e0 + atomicAdd(&cur[p & 255], 1);
        csr[pos] = p >> 8;
    }
}

// ---------------- layer-1 matmul, fp16 out, dis-prescaled, zero row at N ----------------

template <int FIN, int FOUT>
__global__ void k_mm_h(const float* __restrict__ h, const float* __restrict__ W,
                       const float* __restrict__ dis, __half* __restrict__ out) {
    __shared__ float sW[FIN * FOUT];
    for (int i = threadIdx.x; i < FIN * FOUT; i += blockDim.x) sW[i] = W[i];
    __syncthreads();
    int gid = blockIdx.x * blockDim.x + threadIdx.x;
    if (gid >= (N_NODES + 1) * FOUT) return;
    int n = gid / FOUT, f = gid % FOUT;
    if (n == N_NODES) { out[gid] = __float2half(0.f); return; }
    float acc = 0.f;
#pragma unroll
    for (int i = 0; i < FIN; ++i) acc += h[n * FIN + i] * sW[i * FOUT + f];
    out[gid] = __float2half(acc * dis[n]);
}

// ---------------- fused bn-folded matmul on fp16 y (layer 2) ----------------
// y is already relu(conv+bias); out = dis * ( y @ (diag(a)W) + c@W ), fp16

template <int FIN, int FOUT>
__global__ void k_mm_fused(const __half* __restrict__ y, const float* __restrict__ bnp,
                           const float* __restrict__ W, const float* __restrict__ dis,
                           __half* __restrict__ out) {
    __shared__ float sW[FIN * FOUT];
    __shared__ float scb[FOUT];
    for (int i = threadIdx.x; i < FIN * FOUT; i += blockDim.x)
        sW[i] = bnp[i / FOUT] * W[i];
    if (threadIdx.x < FOUT) {
        float cb = 0.f;
#pragma unroll
        for (int r = 0; r < FIN; ++r) cb += bnp[FIN + r] * W[r * FOUT + threadIdx.x];
        scb[threadIdx.x] = cb;
    }
    __syncthreads();
    int gid = blockIdx.x * blockDim.x + threadIdx.x;
    if (gid >= (N_NODES + 1) * FOUT) return;
    int n = gid / FOUT, f = gid % FOUT;
    if (n == N_NODES) { out[gid] = __float2half(0.f); return; }
    float acc = scb[f];
#pragma unroll
    for (int i = 0; i < FIN; ++i)
        acc += __half2float(y[n * FIN + i]) * sW[i * FOUT + f];
    out[gid] = __float2half(acc * dis[n]);
}

// ---------------- layer-3 MFMA matmul prep ----------------

__global__ void k_prepW(const float* __restrict__ bnp, const float* __restrict__ W,
                        __half* __restrict__ wfrag, float* __restrict__ wcb,
                        __half* __restrict__ bufH) {
    int t = threadIdx.x;   // 512 threads
    {
        int g = t >> 6, kq = (t >> 4) & 3, c = t & 15;
#pragma unroll
        for (int j = 0; j < 8; ++j) {
            int k = kq * 8 + j;
            wfrag[(size_t)t * 8 + j] = __float2half(bnp[k] * W[k * 128 + g * 16 + c]);
        }
    }
    if (t < 128) {
        float cb = 0.f;
#pragma unroll
        for (int k = 0; k < 32; ++k) cb += bnp[32 + k] * W[k * 128 + t];
        wcb[t] = cb;
    }
    if (t >= 128 && t < 160) {  // zero row for agg tails
        int q = t - 128;
        ((__half2*)(bufH + (size_t)N_NODES * 128))[q * 2]     = __half2{__float2half(0.f), __float2half(0.f)};
        ((__half2*)(bufH + (size_t)N_NODES * 128))[q * 2 + 1] = __half2{__float2half(0.f), __float2half(0.f)};
    }
}

// ---------------- layer-3 matmul via MFMA 16x16x32 f16, fp16 y input ----------------

__global__ void k_mm_mfma(const __half* __restrict__ y, const __half* __restrict__ wfrag,
                          const float* __restrict__ wcb, const float* __restrict__ dis,
                          __half* __restrict__ out) {
    int wave = threadIdx.x >> 6;
    int lane = threadIdx.x & 63;
    int n0 = (blockIdx.x * 4 + wave) * 16;
    if (n0 >= N_NODES) return;
    int m = lane & 15;
    int kq = lane >> 4;

    int n = n0 + m;
    half8_t af = *(const half8_t*)(y + (size_t)n * 32 + kq * 8);

    float4_t accs[8];
#pragma unroll
    for (int g = 0; g < 8; ++g) {
        float cb = wcb[g * 16 + m];
        float4_t acc = {cb, cb, cb, cb};
        half8_t bf = *(const half8_t*)(wfrag + (size_t)((g * 4 + kq) * 16 + m) * 8);
        accs[g] = __builtin_amdgcn_mfma_f32_16x16x32_f16(af, bf, acc, 0, 0, 0);
    }
    float dnv[4];
#pragma unroll
    for (int r = 0; r < 4; ++r) dnv[r] = dis[n0 + kq * 4 + r];
#pragma unroll
    for (int g = 0; g < 8; ++g)
#pragma unroll
        for (int r = 0; r < 4; ++r)
            out[(size_t)(n0 + kq * 4 + r) * 128 + g * 16 + m] =
                __float2half(accs[g][r] * dnv[r]);
}

// ---------------- GCN aggregation + fused bias/relu/fp16-store ----------------
// yC[n] = relu( dis[n]*(sum_{s} hWd[s] + hWd[n]) + bias ), fp16

struct alignas(8) h4 { __half2 a, b; };

template <int FOUT, int UNROLL>
__global__ void k_agg_v5(const __half* __restrict__ hWd, const int* __restrict__ offs,
                         const int* __restrict__ csr, const float* __restrict__ dis,
                         const float* __restrict__ bias, __half* __restrict__ yC) {
    constexpr int LPE = FOUT / 4;
    constexpr int EPI = 64 / LPE;
    int wave = threadIdx.x >> 6;
    int lane = threadIdx.x & 63;
    int node = blockIdx.x * (blockDim.x >> 6) + wave;
    if (node >= N_NODES) return;
    int chunk = lane % LPE;
    int eg    = lane / LPE;

    int e0 = offs[node], e1 = offs[node + 1];
    float dn = dis[node];
    float ax = 0.f, ay = 0.f, az = 0.f, aw = 0.f;
    const __half* hp = hWd + (size_t)chunk * 4;

    for (int e = e0 + eg; e < e1; e += UNROLL * EPI) {
        int s[UNROLL];
        s[0] = csr[e];
#pragma unroll
        for (int u = 1; u < UNROLL; ++u)
            s[u] = (e + u * EPI < e1) ? csr[e + u * EPI] : N_NODES;
        h4 v[UNROLL];
#pragma unroll
        for (int u = 0; u < UNROLL; ++u)
            v[u] = *(const h4*)(hp + (size_t)s[u] * FOUT);
#pragma unroll
        for (int u = 0; u < UNROLL; ++u) {
            ax += __low2float(v[u].a);
            ay += __high2float(v[u].a);
            az += __low2float(v[u].b);
            aw += __high2float(v[u].b);
        }
    }
    if (eg == 0) {  // self-loop
        h4 v = *(const h4*)(hp + (size_t)node * FOUT);
        ax += __low2float(v.a);
        ay += __high2float(v.a);
        az += __low2float(v.b);
        aw += __high2float(v.b);
    }
#pragma unroll
    for (int off = LPE; off < 64; off <<= 1) {
        ax += __shfl_xor(ax, off, 64);
        ay += __shfl_xor(ay, off, 64);
        az += __shfl_xor(az, off, 64);
        aw += __shfl_xor(aw, off, 64);
    }
    if (lane < LPE) {
        float4 b4 = *(const float4*)(bias + chunk * 4);
        float y0 = fmaxf(dn * ax + b4.x, 0.f);
        float y1 = fmaxf(dn * ay + b4.y, 0.f);
        float y2 = fmaxf(dn * az + b4.z, 0.f);
        float y3 = fmaxf(dn * aw + b4.w, 0.f);
        h4 o;
        o.a = __floats2half2_rn(y0, y1);
        o.b = __floats2half2_rn(y2, y3);
        *(h4*)(yC + (size_t)node * FOUT + chunk * 4) = o;
    }
}

// ---------------- BN stats over fp16 y ----------------

template <int FOUT>
__global__ void k_stats(const __half* __restrict__ y, float* __restrict__ stats) {
    constexpr int GP = 256 / FOUT;
    int f = threadIdx.x % FOUT, g = threadIdx.x / FOUT;
    float s = 0.f, s2 = 0.f;
    for (int n = blockIdx.x * GP + g; n < N_NODES; n += gridDim.x * GP) {
        float v = __half2float(y[(size_t)n * FOUT + f]);
        s += v;
        s2 += v * v;
    }
    __shared__ float ls[256], ls2[256];
    ls[threadIdx.x] = s;
    ls2[threadIdx.x] = s2;
    __syncthreads();
    if (g == 0) {
        for (int gg = 1; gg < GP; ++gg) {
            s += ls[gg * FOUT + f];
            s2 += ls2[gg * FOUT + f];
        }
        atomicAdd(&stats[f], s);
        atomicAdd(&stats[FOUT + f], s2);
    }
}

template <int FOUT>
__global__ void k_bnprep(const float* __restrict__ stats, const float* __restrict__ gamma,
                         const float* __restrict__ beta, float* __restrict__ bnp) {
    int f = threadIdx.x;
    if (f >= FOUT) return;
    float inv_n = 1.0f / (float)N_NODES;
    float m = stats[f] * inv_n;
    float v = stats[FOUT + f] * inv_n - m * m;
    float a = gamma[f] * rsqrtf(v + BN_EPS);
    bnp[f] = a;
    bnp[FOUT + f] = beta[f] - m * a;
}

// ---------------- pool (bn-affine on fp16 y) + head ----------------

__device__ __forceinline__ int lower_bound_dev(const int* __restrict__ a, int val) {
    int lo = 0, hi = N_NODES;
    while (lo < hi) {
        int mid = (lo + hi) >> 1;
        if (a[mid] < val) lo = mid + 1; else hi = mid;
    }
    return lo;
}

__global__ void k_pool(const __half* __restrict__ y, const int* __restrict__ batch,
                       const float* __restrict__ bnp, float* __restrict__ pooled) {
    int g = blockIdx.x;
    int f = threadIdx.x;
    int s = lower_bound_dev(batch, g);
    int e = lower_bound_dev(batch, g + 1);
    float mx = -INFINITY, mn = INFINITY;
    for (int n = s; n < e; ++n) {
        float v = __half2float(y[(size_t)n * 128 + f]);
        mx = fmaxf(mx, v);
        mn = fminf(mn, v);
    }
    float a = bnp[f], c = bnp[128 + f];
    float r;
    if (e > s) r = (a >= 0.f) ? (a * mx + c) : (a * mn + c);
    else r = -INFINITY;
    pooled[g * 128 + f] = r;
}

__global__ void k_head(const float* __restrict__ pooled, const float* __restrict__ Wl,
                       const float* __restrict__ bl, float* __restrict__ out) {
    int g = blockIdx.x * blockDim.x + threadIdx.x;
    if (g >= N_GRAPHS) return;
    float l0 = bl[0], l1 = bl[1], l2 = bl[2];
    for (int i = 0; i < 128; ++i) {
        float p = pooled[g * 128 + i];
        l0 += p * Wl[i * 3 + 0];
        l1 += p * Wl[i * 3 + 1];
        l2 += p * Wl[i * 3 + 2];
    }
    float mx = fmaxf(l0, fmaxf(l1, l2));
    float lse = mx + logf(expf(l0 - mx) + expf(l1 - mx) + expf(l2 - mx));
    out[g * 3 + 0] = l0 - lse;
    out[g * 3 + 1] = l1 - lse;
    out[g * 3 + 2] = l2 - lse;
}

// ---------------- launch ----------------

extern "C" void kernel_launch(void* const* d_in, const int* in_sizes, int n_in,
                              void* d_out, int out_size, void* d_ws, size_t ws_size,
                              hipStream_t stream) {
    const float* x   = (const float*)d_in[0];
    const int* ei    = (const int*)d_in[1];
    const int* src   = ei;
    const int* dst   = ei + N_EDGES;
    const int* batch = (const int*)d_in[2];
    const float *W1 = (const float*)d_in[3],  *b1 = (const float*)d_in[4];
    const float *g1 = (const float*)d_in[5],  *be1 = (const float*)d_in[6];
    const float *W2 = (const float*)d_in[7],  *b2 = (const float*)d_in[8];
    const float *g2 = (const float*)d_in[9],  *be2 = (const float*)d_in[10];
    const float *W3 = (const float*)d_in[11], *b3 = (const float*)d_in[12];
    const float *g3 = (const float*)d_in[13], *be3 = (const float*)d_in[14];
    const float *Wl = (const float*)d_in[15], *bl = (const float*)d_in[16];
    float* out = (float*)d_out;

    // workspace carve (4-byte units, each array 16B-aligned)
    int* base = (int*)d_ws;
    size_t o = 0;
    float* stats1 = (float*)(base + o); o += 256;
    float* stats2 = (float*)(base + o); o += 256;
    float* stats3 = (float*)(base + o); o += 256;
    size_t zero_words = o;
    int* bbase   = base + o; o += NBIN + 1;          // 392
    int* ghist   = base + o; o += 392;
    int* hists   = base + o; o += ((size_t)NBIN * NCHUNK + 3) & ~3ULL;
    float* bnp1  = (float*)(base + o); o += 256;
    float* bnp2  = (float*)(base + o); o += 256;
    float* bnp3  = (float*)(base + o); o += 256;
    __half* wfrag = (__half*)(base + o); o += 2048;
    float* wcb   = (float*)(base + o); o += 128;
    int* offs    = base + o; o += 100004;
    int* store   = base + o; o += N_EDGES;
    int* csr     = base + o; o += N_EDGES;
    float* dis   = (float*)(base + o); o += N_NODES;
    float* pooled= (float*)(base + o); o += (size_t)N_GRAPHS * 128;
    __half* bufH = (__half*)(base + o); o += (size_t)(N_NODES + 1) * 64;  // (N+1)*128 halfs
    __half* yC   = (__half*)(base + o); o += (size_t)N_NODES * 64;        // N*128 halfs
    if (ws_size < o * 4) return;

    const int TB = 256;
    const int gridAgg = (N_NODES + 3) / 4;

    hipMemsetAsync(base, 0, zero_words * 4, stream);

    // CSR build (single-scatter radix)
    k_hist2<<<NCHUNK, TB, 0, stream>>>(dst, hists);
    k_scan2<<<NBIN, 64, 0, stream>>>(hists, ghist);
    k_binscan<<<1, 512, 0, stream>>>(ghist, bbase, offs);
    k_scatter<<<NCHUNK, TB, 0, stream>>>(src, dst, bbase, hists, store);
    k_csr_build<<<NBIN, 256, 0, stream>>>(bbase, store, offs, dis, csr);

    // ---- layer 1: 2 -> 8 ----
    {
        const int g8 = ((N_NODES + 1) * 8 + TB - 1) / TB;
        k_mm_h<2, 8><<<g8, TB, 0, stream>>>(x, W1, dis, bufH);
        k_agg_v5<8, 4><<<gridAgg, TB, 0, stream>>>(bufH, offs, csr, dis, b1, yC);
        k_stats<8><<<256, 256, 0, stream>>>(yC, stats1);
        k_bnprep<8><<<1, 8, 0, stream>>>(stats1, g1, be1, bnp1);
    }
    // ---- layer 2: 8 -> 32 ----
    {
        const int g32 = ((N_NODES + 1) * 32 + TB - 1) / TB;
        k_mm_fused<8, 32><<<g32, TB, 0, stream>>>(yC, bnp1, W2, dis, bufH);
        k_agg_v5<32, 4><<<gridAgg, TB, 0, stream>>>(bufH, offs, csr, dis, b2, yC);
        k_stats<32><<<256, 256, 0, stream>>>(yC, stats2);
        k_bnprep<32><<<1, 32, 0, stream>>>(stats2, g2, be2, bnp2);
    }
    // ---- layer 3: 32 -> 128 (MFMA) ----
    {
        k_prepW<<<1, 512, 0, stream>>>(bnp2, W3, wfrag, wcb, bufH);
        k_mm_mfma<<<(N_NODES + 63) / 64, 256, 0, stream>>>(yC, wfrag, wcb, dis, bufH);
        k_agg_v5<128, 8><<<gridAgg, TB, 0, stream>>>(bufH, offs, csr, dis, b3, yC);
        k_stats<128><<<256, 256, 0, stream>>>(yC, stats3);
        k_bnprep<128><<<1, 128, 0, stream>>>(stats3, g3, be3, bnp3);
    }

    // pool (bn affine) + head
    k_pool<<<N_GRAPHS, 128, 0, stream>>>(yC, batch, bnp3, pooled);
    k_head<<<(N_GRAPHS + TB - 1) / TB, TB, 0, stream>>>(pooled, Wl, bl, out);
}

// Round 7
// 515.420 us; speedup vs baseline: 3.2071x; 1.1776x over previous
//
#include <hip/hip_runtime.h>
#include <hip/hip_bf16.h>
#include <hip/hip_fp16.h>
#include <math.h>

#define N_NODES 100000
#define N_EDGES 3200000
#define N_GRAPHS 512
#define BN_EPS 1e-5f
#define NBIN ((N_NODES + 255) / 256)            // 391 bins of 256 nodes
#define CHUNK 8192                              // edges per chunk block
#define NCHUNK ((N_EDGES + CHUNK - 1) / CHUNK)  // 391

typedef _Float16 half8_t __attribute__((ext_vector_type(8)));
typedef float float4_t __attribute__((ext_vector_type(4)));

struct alignas(8) h4 { __half2 a, b; };
struct alignas(16) h8s { __half2 h[4]; };

// ---------------- CSR build: single-scatter radix ----------------

__global__ void k_hist2(const int* __restrict__ dst, int* __restrict__ hists) {
    __shared__ int h[NBIN];
    for (int i = threadIdx.x; i < NBIN; i += blockDim.x) h[i] = 0;
    __syncthreads();
    int e0 = blockIdx.x * CHUNK;
    int e1 = min(e0 + CHUNK, N_EDGES);
    for (int e = e0 + threadIdx.x; e < e1; e += blockDim.x)
        atomicAdd(&h[dst[e] >> 8], 1);
    __syncthreads();
    for (int i = threadIdx.x; i < NBIN; i += blockDim.x)
        hists[i * NCHUNK + blockIdx.x] = h[i];
}

__global__ void k_scan2(int* __restrict__ hists, int* __restrict__ ghist) {
    int b = blockIdx.x;
    int lane = threadIdx.x;   // 64 threads
    int carry = 0;
    int base = b * NCHUNK;
    for (int c0 = 0; c0 < NCHUNK; c0 += 64) {
        int c = c0 + lane;
        int v = (c < NCHUNK) ? hists[base + c] : 0;
        int inc = v;
#pragma unroll
        for (int off = 1; off < 64; off <<= 1) {
            int u = __shfl_up(inc, off, 64);
            if (lane >= off) inc += u;
        }
        if (c < NCHUNK) hists[base + c] = inc - v + carry;
        carry += __shfl(inc, 63, 64);
    }
    if (lane == 0) ghist[b] = carry;
}

__global__ void k_binscan(const int* __restrict__ ghist, int* __restrict__ bbase,
                          int* __restrict__ offs) {
    __shared__ int sd[512];
    int t = threadIdx.x;
    int v = (t < NBIN) ? ghist[t] : 0;
    sd[t] = v;
    __syncthreads();
    for (int off = 1; off < 512; off <<= 1) {
        int u = (t >= off) ? sd[t - off] : 0;
        __syncthreads();
        sd[t] += u;
        __syncthreads();
    }
    if (t < NBIN) bbase[t] = sd[t] - v;
    if (t == 0) { bbase[NBIN] = N_EDGES; offs[N_NODES] = N_EDGES; }
}

__global__ void k_scatter(const int* __restrict__ src, const int* __restrict__ dst,
                          const int* __restrict__ bbase, const int* __restrict__ hists,
                          int* __restrict__ store) {
    __shared__ int cur[NBIN];
    for (int i = threadIdx.x; i < NBIN; i += blockDim.x)
        cur[i] = bbase[i] + hists[i * NCHUNK + blockIdx.x];
    __syncthreads();
    int e0 = blockIdx.x * CHUNK;
    int e1 = min(e0 + CHUNK, N_EDGES);
    for (int e = e0 + threadIdx.x; e < e1; e += blockDim.x) {
        int d = dst[e];
        int b = d >> 8;
        int pos = atomicAdd(&cur[b], 1);
        store[pos] = (src[e] << 8) | (d & 255);
    }
}

__global__ void k_csr_build(const int* __restrict__ bbase, const int* __restrict__ store,
                            int* __restrict__ offs, float* __restrict__ dis,
                            float* __restrict__ rdis, int* __restrict__ csr) {
    __shared__ int cnt[256], cur[256], wsum[4];
    int b = blockIdx.x;
    int n0 = b << 8;
    int nn = min(256, N_NODES - n0);
    int e0 = bbase[b], e1 = bbase[b + 1];
    int t = threadIdx.x;
    cnt[t] = 0;
    __syncthreads();
    for (int e = e0 + t; e < e1; e += 256) atomicAdd(&cnt[store[e] & 255], 1);
    __syncthreads();
    int c = cnt[t];
    int inc = c;
    int lane = t & 63, wid = t >> 6;
#pragma unroll
    for (int off = 1; off < 64; off <<= 1) {
        int u = __shfl_up(inc, off, 64);
        if (lane >= off) inc += u;
    }
    if (lane == 63) wsum[wid] = inc;
    __syncthreads();
    int wo = 0;
    for (int w = 0; w < wid; ++w) wo += wsum[w];
    int ex = inc - c + wo;
    cur[t] = ex;
    if (t < nn) {
        offs[n0 + t] = e0 + ex;
        dis[n0 + t] = rsqrtf(1.0f + (float)c);
        rdis[n0 + t] = sqrtf(1.0f + (float)c);
    }
    __syncthreads();
    for (int e = e0 + t; e < e1; e += 256) {
        int p = store[e];
        int pos = e0 + atomicAdd(&cur[p & 255], 1);
        csr[pos] = p >> 8;
    }
}

// ---------------- layer 1: aggregate x (width 2) + svec, fused 2->8 mm + relu ----------------
// u0[n] = dis[n]*Sum_s dis[s]*x[s] + dis[n]^2*x[n];  svec[n] = dis[n]*Sum_s dis[s] + dis[n]^2
// ys1[n] = dis[n]*relu(u0[n] @ W1 + b1)  (fp16, width 8)

__global__ void k_agg1(const float* __restrict__ x, const int* __restrict__ offs,
                       const int* __restrict__ csr, const float* __restrict__ dis,
                       const float* __restrict__ W1, const float* __restrict__ b1,
                       float* __restrict__ svec, __half* __restrict__ ys1) {
    __shared__ float sW[16], sb[8];
    int t = threadIdx.x;
    if (t < 16) sW[t] = W1[t];
    if (t < 8) sb[t] = b1[t];
    __syncthreads();
    int wave = t >> 6, lane = t & 63;
    int node = blockIdx.x * 4 + wave;
    if (node >= N_NODES) return;
    int e0 = offs[node], e1 = offs[node + 1];
    float ax = 0.f, ay = 0.f, as = 0.f;
    for (int e = e0 + lane; e < e1; e += 64) {
        int s = csr[e];
        float ds = dis[s];
        float2 xv = *(const float2*)(x + 2 * (size_t)s);
        ax += ds * xv.x;
        ay += ds * xv.y;
        as += ds;
    }
#pragma unroll
    for (int off = 1; off < 64; off <<= 1) {
        ax += __shfl_xor(ax, off, 64);
        ay += __shfl_xor(ay, off, 64);
        as += __shfl_xor(as, off, 64);
    }
    if (lane == 0) {
        float dn = dis[node];
        float2 xn = *(const float2*)(x + 2 * (size_t)node);
        float u0x = dn * ax + dn * dn * xn.x;
        float u0y = dn * ay + dn * dn * xn.y;
        svec[node] = dn * as + dn * dn;
        float y[8];
#pragma unroll
        for (int f = 0; f < 8; ++f)
            y[f] = dn * fmaxf(u0x * sW[f] + u0y * sW[8 + f] + sb[f], 0.f);
        h8s o;
#pragma unroll
        for (int q = 0; q < 4; ++q) o.h[q] = __floats2half2_rn(y[2 * q], y[2 * q + 1]);
        *(h8s*)(ys1 + (size_t)node * 8) = o;
    }
}

// ---------------- prep2: bnp1 from stats1, W2p = diag(a1)W2, cw2 = c1@W2 ----------------

__global__ void k_prep2(const float* __restrict__ stats, const float* __restrict__ gamma,
                        const float* __restrict__ beta, const float* __restrict__ W2,
                        float* __restrict__ W2p, float* __restrict__ cw2) {
    __shared__ float a1[8], c1[8];
    int t = threadIdx.x;   // 256
    if (t < 8) {
        float inv_n = 1.0f / (float)N_NODES;
        float m = stats[t] * inv_n;
        float v = stats[8 + t] * inv_n - m * m;
        float a = gamma[t] * rsqrtf(v + BN_EPS);
        a1[t] = a;
        c1[t] = beta[t] - m * a;
    }
    __syncthreads();
    W2p[t] = a1[t >> 5] * W2[t];    // 8x32 = 256
    if (t < 32) {
        float cb = 0.f;
#pragma unroll
        for (int i = 0; i < 8; ++i) cb += c1[i] * W2[i * 32 + t];
        cw2[t] = cb;
    }
}

// ---------------- layer 2: aggregate ys1 (width 8), fused 8->32 mm + relu ----------------
// u1 = dis[n]*(Sum ys1[s] + ys1[n]);  ys2[n] = dis[n]*relu(u1@W2p + svec[n]*cw2 + b2)

__global__ void k_agg2(const __half* __restrict__ ys1, const int* __restrict__ offs,
                       const int* __restrict__ csr, const float* __restrict__ dis,
                       const float* __restrict__ svec, const float* __restrict__ W2p,
                       const float* __restrict__ cw2, const float* __restrict__ b2,
                       __half* __restrict__ ys2) {
    __shared__ float sW[256], sC[32], sB[32];
    int t = threadIdx.x;
    sW[t] = W2p[t];
    if (t < 32) { sC[t] = cw2[t]; sB[t] = b2[t]; }
    __syncthreads();
    int wave = t >> 6, lane = t & 63;
    int node = blockIdx.x * 4 + wave;
    if (node >= N_NODES) return;
    int e0 = offs[node], e1 = offs[node + 1];
    float acc[8] = {0.f, 0.f, 0.f, 0.f, 0.f, 0.f, 0.f, 0.f};
    for (int e = e0 + lane; e < e1; e += 64) {
        int s = csr[e];
        h8s v = *(const h8s*)(ys1 + (size_t)s * 8);
#pragma unroll
        for (int q = 0; q < 4; ++q) {
            acc[2 * q]     += __low2float(v.h[q]);
            acc[2 * q + 1] += __high2float(v.h[q]);
        }
    }
    if (lane == 0) {   // self-loop
        h8s v = *(const h8s*)(ys1 + (size_t)node * 8);
#pragma unroll
        for (int q = 0; q < 4; ++q) {
            acc[2 * q]     += __low2float(v.h[q]);
            acc[2 * q + 1] += __high2float(v.h[q]);
        }
    }
#pragma unroll
    for (int off = 1; off < 64; off <<= 1)
#pragma unroll
        for (int i = 0; i < 8; ++i) acc[i] += __shfl_xor(acc[i], off, 64);
    if (lane < 32) {
        float dn = dis[node];
        float conv = sB[lane] + svec[node] * sC[lane];
#pragma unroll
        for (int i = 0; i < 8; ++i) conv += (dn * acc[i]) * sW[i * 32 + lane];
        ys2[(size_t)node * 32 + lane] = __float2half(dn * fmaxf(conv, 0.f));
    }
}

// ---------------- prep3: bnp2 -> W3 fragments (fp16) + cw3; zero row ys2[N] ----------------
// wfrag slot t=(g*4+kq)*16+c, entry j: a2[k]*W3[k*128 + g*16+c], k=kq*8+j

__global__ void k_prep3(const float* __restrict__ stats, const float* __restrict__ gamma,
                        const float* __restrict__ beta, const float* __restrict__ W3,
                        __half* __restrict__ wfrag, float* __restrict__ cw3,
                        __half* __restrict__ ys2) {
    __shared__ float a2[32], c2[32];
    int t = threadIdx.x;   // 512
    if (t < 32) {
        float inv_n = 1.0f / (float)N_NODES;
        float m = stats[t] * inv_n;
        float v = stats[32 + t] * inv_n - m * m;
        float a = gamma[t] * rsqrtf(v + BN_EPS);
        a2[t] = a;
        c2[t] = beta[t] - m * a;
    }
    __syncthreads();
    {
        int g = t >> 6, kq = (t >> 4) & 3, c = t & 15;
#pragma unroll
        for (int j = 0; j < 8; ++j) {
            int k = kq * 8 + j;
            wfrag[(size_t)t * 8 + j] = __float2half(a2[k] * W3[k * 128 + g * 16 + c]);
        }
    }
    if (t < 128) {
        float cb = 0.f;
#pragma unroll
        for (int k = 0; k < 32; ++k) cb += c2[k] * W3[k * 128 + t];
        cw3[t] = cb;
    }
    if (t >= 480 && t < 496)   // zero row ys2[N_NODES] (64 B)
        ((__half2*)(ys2 + (size_t)N_NODES * 32))[t - 480] =
            __half2{__float2half(0.f), __float2half(0.f)};
}

// ---------------- layer 3 aggregation: ys2 (width 32) -> u2 ----------------
// u2[n] = dis[n]*(Sum ys2[s] + ys2[n])  (fp16)

__global__ void k_agg3(const __half* __restrict__ ys2, const int* __restrict__ offs,
                       const int* __restrict__ csr, const float* __restrict__ dis,
                       __half* __restrict__ u2) {
    int wave = threadIdx.x >> 6;
    int lane = threadIdx.x & 63;
    int node = blockIdx.x * 4 + wave;
    if (node >= N_NODES) return;
    int chunk = lane & 7;   // 8 feature-chunks of 4
    int eg = lane >> 3;     // 8 edge-groups
    int e0 = offs[node], e1 = offs[node + 1];
    float ax = 0.f, ay = 0.f, az = 0.f, aw = 0.f;
    const __half* hp = ys2 + (size_t)chunk * 4;
    for (int e = e0 + eg; e < e1; e += 32) {
        int s0 = csr[e];
        int s1 = (e + 8 < e1) ? csr[e + 8] : N_NODES;
        int s2 = (e + 16 < e1) ? csr[e + 16] : N_NODES;
        int s3 = (e + 24 < e1) ? csr[e + 24] : N_NODES;
        h4 v0 = *(const h4*)(hp + (size_t)s0 * 32);
        h4 v1 = *(const h4*)(hp + (size_t)s1 * 32);
        h4 v2 = *(const h4*)(hp + (size_t)s2 * 32);
        h4 v3 = *(const h4*)(hp + (size_t)s3 * 32);
        ax += __low2float(v0.a) + __low2float(v1.a) + __low2float(v2.a) + __low2float(v3.a);
        ay += __high2float(v0.a) + __high2float(v1.a) + __high2float(v2.a) + __high2float(v3.a);
        az += __low2float(v0.b) + __low2float(v1.b) + __low2float(v2.b) + __low2float(v3.b);
        aw += __high2float(v0.b) + __high2float(v1.b) + __high2float(v2.b) + __high2float(v3.b);
    }
    if (eg == 0) {   // self-loop
        h4 v = *(const h4*)(hp + (size_t)node * 32);
        ax += __low2float(v.a);
        ay += __high2float(v.a);
        az += __low2float(v.b);
        aw += __high2float(v.b);
    }
#pragma unroll
    for (int off = 8; off < 64; off <<= 1) {
        ax += __shfl_xor(ax, off, 64);
        ay += __shfl_xor(ay, off, 64);
        az += __shfl_xor(az, off, 64);
        aw += __shfl_xor(aw, off, 64);
    }
    if (lane < 8) {
        float dn = dis[node];
        h4 o;
        o.a = __floats2half2_rn(dn * ax, dn * ay);
        o.b = __floats2half2_rn(dn * az, dn * aw);
        *(h4*)(u2 + (size_t)node * 32 + chunk * 4) = o;
    }
}

// ---------------- layer 3 transform via MFMA: ys3 = dis*relu(u2@W3p + svec*cw3 + b3) ----------------

__global__ void k_mm_mfma(const __half* __restrict__ u2, const __half* __restrict__ wfrag,
                          const float* __restrict__ cw3, const float* __restrict__ b3,
                          const float* __restrict__ svec, const float* __restrict__ dis,
                          __half* __restrict__ ys3) {
    int wave = threadIdx.x >> 6;
    int lane = threadIdx.x & 63;
    int n0 = (blockIdx.x * 4 + wave) * 16;
    if (n0 >= N_NODES) return;
    int m = lane & 15;
    int kq = lane >> 4;

    half8_t af = *(const half8_t*)(u2 + (size_t)(n0 + m) * 32 + kq * 8);

    float4_t accs[8];
#pragma unroll
    for (int g = 0; g < 8; ++g) {
        float4_t acc = {0.f, 0.f, 0.f, 0.f};
        half8_t bf = *(const half8_t*)(wfrag + (size_t)((g * 4 + kq) * 16 + m) * 8);
        accs[g] = __builtin_amdgcn_mfma_f32_16x16x32_f16(af, bf, acc, 0, 0, 0);
    }
    float sv[4], dn[4];
#pragma unroll
    for (int r = 0; r < 4; ++r) {
        sv[r] = svec[n0 + kq * 4 + r];
        dn[r] = dis[n0 + kq * 4 + r];
    }
#pragma unroll
    for (int g = 0; g < 8; ++g) {
        float cwf = cw3[g * 16 + m];
        float bf3 = b3[g * 16 + m];
#pragma unroll
        for (int r = 0; r < 4; ++r) {
            float y = fmaxf(accs[g][r] + sv[r] * cwf + bf3, 0.f);
            ys3[(size_t)(n0 + kq * 4 + r) * 128 + g * 16 + m] = __float2half(dn[r] * y);
        }
    }
}

// ---------------- BN stats over y = ys * rdis ----------------

template <int FOUT>
__global__ void k_stats(const __half* __restrict__ ys, const float* __restrict__ rdis,
                        float* __restrict__ stats) {
    constexpr int GP = 256 / FOUT;
    int f = threadIdx.x % FOUT, g = threadIdx.x / FOUT;
    float s = 0.f, s2 = 0.f;
    for (int n = blockIdx.x * GP + g; n < N_NODES; n += gridDim.x * GP) {
        float v = __half2float(ys[(size_t)n * FOUT + f]) * rdis[n];
        s += v;
        s2 += v * v;
    }
    __shared__ float ls[256], ls2[256];
    ls[threadIdx.x] = s;
    ls2[threadIdx.x] = s2;
    __syncthreads();
    if (g == 0) {
        for (int gg = 1; gg < GP; ++gg) {
            s += ls[gg * FOUT + f];
            s2 += ls2[gg * FOUT + f];
        }
        atomicAdd(&stats[f], s);
        atomicAdd(&stats[FOUT + f], s2);
    }
}

// ---------------- pool (bn affine inline) + head ----------------

__device__ __forceinline__ int lower_bound_dev(const int* __restrict__ a, int val) {
    int lo = 0, hi = N_NODES;
    while (lo < hi) {
        int mid = (lo + hi) >> 1;
        if (a[mid] < val) lo = mid + 1; else hi = mid;
    }
    return lo;
}

__global__ void k_pool(const __half* __restrict__ ys3, const float* __restrict__ rdis,
                       const int* __restrict__ batch, const float* __restrict__ stats,
                       const float* __restrict__ gamma, const float* __restrict__ beta,
                       float* __restrict__ pooled) {
    int g = blockIdx.x;
    int f = threadIdx.x;
    float inv_n = 1.0f / (float)N_NODES;
    float m = stats[f] * inv_n;
    float var = stats[128 + f] * inv_n - m * m;
    float a = gamma[f] * rsqrtf(var + BN_EPS);
    float c = beta[f] - m * a;
    int s = lower_bound_dev(batch, g);
    int e = lower_bound_dev(batch, g + 1);
    float mx = -INFINITY, mn = INFINITY;
    for (int n = s; n < e; ++n) {
        float v = __half2float(ys3[(size_t)n * 128 + f]) * rdis[n];
        mx = fmaxf(mx, v);
        mn = fminf(mn, v);
    }
    float r;
    if (e > s) r = (a >= 0.f) ? (a * mx + c) : (a * mn + c);
    else r = -INFINITY;
    pooled[g * 128 + f] = r;
}

__global__ void k_head(const float* __restrict__ pooled, const float* __restrict__ Wl,
                       const float* __restrict__ bl, float* __restrict__ out) {
    int g = blockIdx.x * blockDim.x + threadIdx.x;
    if (g >= N_GRAPHS) return;
    float l0 = bl[0], l1 = bl[1], l2 = bl[2];
    for (int i = 0; i < 128; ++i) {
        float p = pooled[g * 128 + i];
        l0 += p * Wl[i * 3 + 0];
        l1 += p * Wl[i * 3 + 1];
        l2 += p * Wl[i * 3 + 2];
    }
    float mx = fmaxf(l0, fmaxf(l1, l2));
    float lse = mx + logf(expf(l0 - mx) + expf(l1 - mx) + expf(l2 - mx));
    out[g * 3 + 0] = l0 - lse;
    out[g * 3 + 1] = l1 - lse;
    out[g * 3 + 2] = l2 - lse;
}

// ---------------- launch ----------------

extern "C" void kernel_launch(void* const* d_in, const int* in_sizes, int n_in,
                              void* d_out, int out_size, void* d_ws, size_t ws_size,
                              hipStream_t stream) {
    const float* x   = (const float*)d_in[0];
    const int* ei    = (const int*)d_in[1];
    const int* src   = ei;
    const int* dst   = ei + N_EDGES;
    const int* batch = (const int*)d_in[2];
    const float *W1 = (const float*)d_in[3],  *b1 = (const float*)d_in[4];
    const float *g1 = (const float*)d_in[5],  *be1 = (const float*)d_in[6];
    const float *W2 = (const float*)d_in[7],  *b2 = (const float*)d_in[8];
    const float *g2 = (const float*)d_in[9],  *be2 = (const float*)d_in[10];
    const float *W3 = (const float*)d_in[11], *b3 = (const float*)d_in[12];
    const float *g3 = (const float*)d_in[13], *be3 = (const float*)d_in[14];
    const float *Wl = (const float*)d_in[15], *bl = (const float*)d_in[16];
    float* out = (float*)d_out;

    // workspace carve (4-byte words, all sizes multiples of 4 -> 16B alignment)
    int* base = (int*)d_ws;
    size_t o = 0;
    float* stats1 = (float*)(base + o); o += 256;
    float* stats2 = (float*)(base + o); o += 256;
    float* stats3 = (float*)(base + o); o += 256;
    size_t zero_words = o;
    int* bbase    = base + o; o += 392;
    int* ghist    = base + o; o += 392;
    int* hists    = base + o; o += ((size_t)NBIN * NCHUNK + 3) & ~3ULL;
    float* W2p    = (float*)(base + o); o += 256;
    float* cw2    = (float*)(base + o); o += 32;
    __half* wfrag = (__half*)(base + o); o += 2048;
    float* cw3    = (float*)(base + o); o += 128;
    int* offs     = base + o; o += 100004;
    int* store    = base + o; o += N_EDGES;
    int* csr      = base + o; o += N_EDGES;
    float* dis    = (float*)(base + o); o += N_NODES;
    float* rdis   = (float*)(base + o); o += N_NODES;
    float* svec   = (float*)(base + o); o += N_NODES;
    float* pooled = (float*)(base + o); o += (size_t)N_GRAPHS * 128;
    __half* ys1   = (__half*)(base + o); o += (size_t)(N_NODES + 1) * 4;   // (N+1)*8 halfs
    __half* ys2   = (__half*)(base + o); o += (size_t)(N_NODES + 1) * 16;  // (N+1)*32 halfs
    __half* u2    = (__half*)(base + o); o += (size_t)N_NODES * 16;        // N*32 halfs
    __half* ys3   = (__half*)(base + o); o += (size_t)N_NODES * 64;        // N*128 halfs
    if (ws_size < o * 4) return;

    const int TB = 256;
    const int gridAgg = (N_NODES + 3) / 4;   // wave per node, 4 waves/block

    hipMemsetAsync(base, 0, zero_words * 4, stream);

    // CSR build
    k_hist2<<<NCHUNK, TB, 0, stream>>>(dst, hists);
    k_scan2<<<NBIN, 64, 0, stream>>>(hists, ghist);
    k_binscan<<<1, 512, 0, stream>>>(ghist, bbase, offs);
    k_scatter<<<NCHUNK, TB, 0, stream>>>(src, dst, bbase, hists, store);
    k_csr_build<<<NBIN, 256, 0, stream>>>(bbase, store, offs, dis, rdis, csr);

    // layer 1: aggregate x (width 2) + fused 2->8 mm/relu; also svec
    k_agg1<<<gridAgg, TB, 0, stream>>>(x, offs, csr, dis, W1, b1, svec, ys1);
    k_stats<8><<<256, 256, 0, stream>>>(ys1, rdis, stats1);
    k_prep2<<<1, 256, 0, stream>>>(stats1, g1, be1, W2, W2p, cw2);

    // layer 2: aggregate ys1 (width 8) + fused 8->32 mm/relu
    k_agg2<<<gridAgg, TB, 0, stream>>>(ys1, offs, csr, dis, svec, W2p, cw2, b2, ys2);
    k_stats<32><<<256, 256, 0, stream>>>(ys2, rdis, stats2);
    k_prep3<<<1, 512, 0, stream>>>(stats2, g2, be2, W3, wfrag, cw3, ys2);

    // layer 3: aggregate ys2 (width 32), then MFMA 32->128 + relu
    k_agg3<<<gridAgg, TB, 0, stream>>>(ys2, offs, csr, dis, u2);
    k_mm_mfma<<<(N_NODES + 63) / 64, 256, 0, stream>>>(u2, wfrag, cw3, b3, svec, dis, ys3);
    k_stats<128><<<256, 256, 0, stream>>>(ys3, rdis, stats3);

    // pool (bn affine inline) + head
    k_pool<<<N_GRAPHS, 128, 0, stream>>>(ys3, rdis, batch, stats3, g3, be3, pooled);
    k_head<<<(N_GRAPHS + TB - 1) / TB, TB, 0, stream>>>(pooled, Wl, bl, out);
}

// Round 8
// 491.232 us; speedup vs baseline: 3.3650x; 1.0492x over previous
//
#include <hip/hip_runtime.h>
#include <hip/hip_bf16.h>
#include <hip/hip_fp16.h>
#include <math.h>

#define N_NODES 100000
#define N_EDGES 3200000
#define N_GRAPHS 512
#define BN_EPS 1e-5f
#define NBIN ((N_NODES + 255) / 256)            // 391 bins of 256 nodes
#define CHUNK 8192                              // edges per chunk block
#define NCHUNK ((N_EDGES + CHUNK - 1) / CHUNK)  // 391
#define LSEG 98
#define NSEGB ((N_NODES + LSEG - 1) / LSEG)     // 1021 pool segments

typedef _Float16 half8_t __attribute__((ext_vector_type(8)));
typedef float float4_t __attribute__((ext_vector_type(4)));

struct alignas(8) h4 { __half2 a, b; };
struct alignas(16) h8s { __half2 h[4]; };

// ---------------- CSR build: single-scatter radix ----------------

__global__ void k_hist2(const int* __restrict__ dst, int* __restrict__ hists) {
    __shared__ int h[NBIN];
    for (int i = threadIdx.x; i < NBIN; i += blockDim.x) h[i] = 0;
    __syncthreads();
    int e0 = blockIdx.x * CHUNK;
    int e1 = min(e0 + CHUNK, N_EDGES);
    for (int e = e0 + threadIdx.x; e < e1; e += blockDim.x)
        atomicAdd(&h[dst[e] >> 8], 1);
    __syncthreads();
    for (int i = threadIdx.x; i < NBIN; i += blockDim.x)
        hists[i * NCHUNK + blockIdx.x] = h[i];
}

__global__ void k_scan2(int* __restrict__ hists, int* __restrict__ ghist) {
    int b = blockIdx.x;
    int lane = threadIdx.x;   // 64 threads
    int carry = 0;
    int base = b * NCHUNK;
    for (int c0 = 0; c0 < NCHUNK; c0 += 64) {
        int c = c0 + lane;
        int v = (c < NCHUNK) ? hists[base + c] : 0;
        int inc = v;
#pragma unroll
        for (int off = 1; off < 64; off <<= 1) {
            int u = __shfl_up(inc, off, 64);
            if (lane >= off) inc += u;
        }
        if (c < NCHUNK) hists[base + c] = inc - v + carry;
        carry += __shfl(inc, 63, 64);
    }
    if (lane == 0) ghist[b] = carry;
}

__global__ void k_binscan(const int* __restrict__ ghist, int* __restrict__ bbase,
                          int* __restrict__ offs) {
    __shared__ int sd[512];
    int t = threadIdx.x;
    int v = (t < NBIN) ? ghist[t] : 0;
    sd[t] = v;
    __syncthreads();
    for (int off = 1; off < 512; off <<= 1) {
        int u = (t >= off) ? sd[t - off] : 0;
        __syncthreads();
        sd[t] += u;
        __syncthreads();
    }
    if (t < NBIN) bbase[t] = sd[t] - v;
    if (t == 0) { bbase[NBIN] = N_EDGES; offs[N_NODES] = N_EDGES; }
}

__global__ void k_scatter(const int* __restrict__ src, const int* __restrict__ dst,
                          const int* __restrict__ bbase, const int* __restrict__ hists,
                          int* __restrict__ store) {
    __shared__ int cur[NBIN];
    for (int i = threadIdx.x; i < NBIN; i += blockDim.x)
        cur[i] = bbase[i] + hists[i * NCHUNK + blockIdx.x];
    __syncthreads();
    int e0 = blockIdx.x * CHUNK;
    int e1 = min(e0 + CHUNK, N_EDGES);
    for (int e = e0 + threadIdx.x; e < e1; e += blockDim.x) {
        int d = dst[e];
        int b = d >> 8;
        int pos = atomicAdd(&cur[b], 1);
        store[pos] = (src[e] << 8) | (d & 255);
    }
}

__global__ void k_csr_build(const int* __restrict__ bbase, const int* __restrict__ store,
                            int* __restrict__ offs, float* __restrict__ dis,
                            float* __restrict__ rdis, int* __restrict__ csr) {
    __shared__ int cnt[256], cur[256], wsum[4];
    int b = blockIdx.x;
    int n0 = b << 8;
    int nn = min(256, N_NODES - n0);
    int e0 = bbase[b], e1 = bbase[b + 1];
    int t = threadIdx.x;
    cnt[t] = 0;
    __syncthreads();
    for (int e = e0 + t; e < e1; e += 256) atomicAdd(&cnt[store[e] & 255], 1);
    __syncthreads();
    int c = cnt[t];
    int inc = c;
    int lane = t & 63, wid = t >> 6;
#pragma unroll
    for (int off = 1; off < 64; off <<= 1) {
        int u = __shfl_up(inc, off, 64);
        if (lane >= off) inc += u;
    }
    if (lane == 63) wsum[wid] = inc;
    __syncthreads();
    int wo = 0;
    for (int w = 0; w < wid; ++w) wo += wsum[w];
    int ex = inc - c + wo;
    cur[t] = ex;
    if (t < nn) {
        offs[n0 + t] = e0 + ex;
        dis[n0 + t] = rsqrtf(1.0f + (float)c);
        rdis[n0 + t] = sqrtf(1.0f + (float)c);
    }
    __syncthreads();
    for (int e = e0 + t; e < e1; e += 256) {
        int p = store[e];
        int pos = e0 + atomicAdd(&cur[p & 255], 1);
        csr[pos] = p >> 8;
    }
}

// ---------------- layer 1: aggregate x (width 2) + svec, fused 2->8 mm + relu ----------------

__global__ void k_agg1(const float* __restrict__ x, const int* __restrict__ offs,
                       const int* __restrict__ csr, const float* __restrict__ dis,
                       const float* __restrict__ W1, const float* __restrict__ b1,
                       float* __restrict__ svec, __half* __restrict__ ys1) {
    __shared__ float sW[16], sb[8];
    int t = threadIdx.x;
    if (t < 16) sW[t] = W1[t];
    if (t < 8) sb[t] = b1[t];
    __syncthreads();
    int wave = t >> 6, lane = t & 63;
    int node = blockIdx.x * 4 + wave;
    if (node >= N_NODES) return;
    int e0 = offs[node], e1 = offs[node + 1];
    float ax = 0.f, ay = 0.f, as = 0.f;
    for (int e = e0 + lane; e < e1; e += 64) {
        int s = csr[e];
        float ds = dis[s];
        float2 xv = *(const float2*)(x + 2 * (size_t)s);
        ax += ds * xv.x;
        ay += ds * xv.y;
        as += ds;
    }
#pragma unroll
    for (int off = 1; off < 64; off <<= 1) {
        ax += __shfl_xor(ax, off, 64);
        ay += __shfl_xor(ay, off, 64);
        as += __shfl_xor(as, off, 64);
    }
    if (lane == 0) {
        float dn = dis[node];
        float2 xn = *(const float2*)(x + 2 * (size_t)node);
        float u0x = dn * ax + dn * dn * xn.x;
        float u0y = dn * ay + dn * dn * xn.y;
        svec[node] = dn * as + dn * dn;
        float y[8];
#pragma unroll
        for (int f = 0; f < 8; ++f)
            y[f] = dn * fmaxf(u0x * sW[f] + u0y * sW[8 + f] + sb[f], 0.f);
        h8s o;
#pragma unroll
        for (int q = 0; q < 4; ++q) o.h[q] = __floats2half2_rn(y[2 * q], y[2 * q + 1]);
        *(h8s*)(ys1 + (size_t)node * 8) = o;
    }
}

// ---------------- prep2 ----------------

__global__ void k_prep2(const float* __restrict__ stats, const float* __restrict__ gamma,
                        const float* __restrict__ beta, const float* __restrict__ W2,
                        float* __restrict__ W2p, float* __restrict__ cw2) {
    __shared__ float a1[8], c1[8];
    int t = threadIdx.x;   // 256
    if (t < 8) {
        float inv_n = 1.0f / (float)N_NODES;
        float m = stats[t] * inv_n;
        float v = stats[8 + t] * inv_n - m * m;
        float a = gamma[t] * rsqrtf(v + BN_EPS);
        a1[t] = a;
        c1[t] = beta[t] - m * a;
    }
    __syncthreads();
    W2p[t] = a1[t >> 5] * W2[t];    // 8x32 = 256
    if (t < 32) {
        float cb = 0.f;
#pragma unroll
        for (int i = 0; i < 8; ++i) cb += c1[i] * W2[i * 32 + t];
        cw2[t] = cb;
    }
}

// ---------------- layer 2: aggregate ys1 (width 8), fused 8->32 mm + relu ----------------

__global__ void k_agg2(const __half* __restrict__ ys1, const int* __restrict__ offs,
                       const int* __restrict__ csr, const float* __restrict__ dis,
                       const float* __restrict__ svec, const float* __restrict__ W2p,
                       const float* __restrict__ cw2, const float* __restrict__ b2,
                       __half* __restrict__ ys2) {
    __shared__ float sW[256], sC[32], sB[32];
    int t = threadIdx.x;
    sW[t] = W2p[t];
    if (t < 32) { sC[t] = cw2[t]; sB[t] = b2[t]; }
    __syncthreads();
    int wave = t >> 6, lane = t & 63;
    int node = blockIdx.x * 4 + wave;
    if (node >= N_NODES) return;
    int e0 = offs[node], e1 = offs[node + 1];
    float acc[8] = {0.f, 0.f, 0.f, 0.f, 0.f, 0.f, 0.f, 0.f};
    for (int e = e0 + lane; e < e1; e += 64) {
        int s = csr[e];
        h8s v = *(const h8s*)(ys1 + (size_t)s * 8);
#pragma unroll
        for (int q = 0; q < 4; ++q) {
            acc[2 * q]     += __low2float(v.h[q]);
            acc[2 * q + 1] += __high2float(v.h[q]);
        }
    }
    if (lane == 0) {   // self-loop
        h8s v = *(const h8s*)(ys1 + (size_t)node * 8);
#pragma unroll
        for (int q = 0; q < 4; ++q) {
            acc[2 * q]     += __low2float(v.h[q]);
            acc[2 * q + 1] += __high2float(v.h[q]);
        }
    }
#pragma unroll
    for (int off = 1; off < 64; off <<= 1)
#pragma unroll
        for (int i = 0; i < 8; ++i) acc[i] += __shfl_xor(acc[i], off, 64);
    if (lane < 32) {
        float dn = dis[node];
        float conv = sB[lane] + svec[node] * sC[lane];
#pragma unroll
        for (int i = 0; i < 8; ++i) conv += (dn * acc[i]) * sW[i * 32 + lane];
        ys2[(size_t)node * 32 + lane] = __float2half(dn * fmaxf(conv, 0.f));
    }
}

// ---------------- prep3 ----------------

__global__ void k_prep3(const float* __restrict__ stats, const float* __restrict__ gamma,
                        const float* __restrict__ beta, const float* __restrict__ W3,
                        __half* __restrict__ wfrag, float* __restrict__ cw3,
                        __half* __restrict__ ys2) {
    __shared__ float a2[32], c2[32];
    int t = threadIdx.x;   // 512
    if (t < 32) {
        float inv_n = 1.0f / (float)N_NODES;
        float m = stats[t] * inv_n;
        float v = stats[32 + t] * inv_n - m * m;
        float a = gamma[t] * rsqrtf(v + BN_EPS);
        a2[t] = a;
        c2[t] = beta[t] - m * a;
    }
    __syncthreads();
    {
        int g = t >> 6, kq = (t >> 4) & 3, c = t & 15;
#pragma unroll
        for (int j = 0; j < 8; ++j) {
            int k = kq * 8 + j;
            wfrag[(size_t)t * 8 + j] = __float2half(a2[k] * W3[k * 128 + g * 16 + c]);
        }
    }
    if (t < 128) {
        float cb = 0.f;
#pragma unroll
        for (int k = 0; k < 32; ++k) cb += c2[k] * W3[k * 128 + t];
        cw3[t] = cb;
    }
    if (t >= 480 && t < 496)
        ((__half2*)(ys2 + (size_t)N_NODES * 32))[t - 480] =
            __half2{__float2half(0.f), __float2half(0.f)};
}

// ---------------- layer 3 aggregation: ys2 (width 32) -> u2 ----------------

__global__ void k_agg3(const __half* __restrict__ ys2, const int* __restrict__ offs,
                       const int* __restrict__ csr, const float* __restrict__ dis,
                       __half* __restrict__ u2) {
    int wave = threadIdx.x >> 6;
    int lane = threadIdx.x & 63;
    int node = blockIdx.x * 4 + wave;
    if (node >= N_NODES) return;
    int chunk = lane & 7;
    int eg = lane >> 3;
    int e0 = offs[node], e1 = offs[node + 1];
    float ax = 0.f, ay = 0.f, az = 0.f, aw = 0.f;
    const __half* hp = ys2 + (size_t)chunk * 4;
    for (int e = e0 + eg; e < e1; e += 32) {
        int s0 = csr[e];
        int s1 = (e + 8 < e1) ? csr[e + 8] : N_NODES;
        int s2 = (e + 16 < e1) ? csr[e + 16] : N_NODES;
        int s3 = (e + 24 < e1) ? csr[e + 24] : N_NODES;
        h4 v0 = *(const h4*)(hp + (size_t)s0 * 32);
        h4 v1 = *(const h4*)(hp + (size_t)s1 * 32);
        h4 v2 = *(const h4*)(hp + (size_t)s2 * 32);
        h4 v3 = *(const h4*)(hp + (size_t)s3 * 32);
        ax += __low2float(v0.a) + __low2float(v1.a) + __low2float(v2.a) + __low2float(v3.a);
        ay += __high2float(v0.a) + __high2float(v1.a) + __high2float(v2.a) + __high2float(v3.a);
        az += __low2float(v0.b) + __low2float(v1.b) + __low2float(v2.b) + __low2float(v3.b);
        aw += __high2float(v0.b) + __high2float(v1.b) + __high2float(v2.b) + __high2float(v3.b);
    }
    if (eg == 0) {
        h4 v = *(const h4*)(hp + (size_t)node * 32);
        ax += __low2float(v.a);
        ay += __high2float(v.a);
        az += __low2float(v.b);
        aw += __high2float(v.b);
    }
#pragma unroll
    for (int off = 8; off < 64; off <<= 1) {
        ax += __shfl_xor(ax, off, 64);
        ay += __shfl_xor(ay, off, 64);
        az += __shfl_xor(az, off, 64);
        aw += __shfl_xor(aw, off, 64);
    }
    if (lane < 8) {
        float dn = dis[node];
        h4 o;
        o.a = __floats2half2_rn(dn * ax, dn * ay);
        o.b = __floats2half2_rn(dn * az, dn * aw);
        *(h4*)(u2 + (size_t)node * 32 + chunk * 4) = o;
    }
}

// ---------------- layer 3 transform via MFMA ----------------

__global__ void k_mm_mfma(const __half* __restrict__ u2, const __half* __restrict__ wfrag,
                          const float* __restrict__ cw3, const float* __restrict__ b3,
                          const float* __restrict__ svec, const float* __restrict__ dis,
                          __half* __restrict__ ys3) {
    int wave = threadIdx.x >> 6;
    int lane = threadIdx.x & 63;
    int n0 = (blockIdx.x * 4 + wave) * 16;
    if (n0 >= N_NODES) return;
    int m = lane & 15;
    int kq = lane >> 4;

    half8_t af = *(const half8_t*)(u2 + (size_t)(n0 + m) * 32 + kq * 8);

    float4_t accs[8];
#pragma unroll
    for (int g = 0; g < 8; ++g) {
        float4_t acc = {0.f, 0.f, 0.f, 0.f};
        half8_t bf = *(const half8_t*)(wfrag + (size_t)((g * 4 + kq) * 16 + m) * 8);
        accs[g] = __builtin_amdgcn_mfma_f32_16x16x32_f16(af, bf, acc, 0, 0, 0);
    }
    float sv[4], dn[4];
#pragma unroll
    for (int r = 0; r < 4; ++r) {
        sv[r] = svec[n0 + kq * 4 + r];
        dn[r] = dis[n0 + kq * 4 + r];
    }
#pragma unroll
    for (int g = 0; g < 8; ++g) {
        float cwf = cw3[g * 16 + m];
        float bf3 = b3[g * 16 + m];
#pragma unroll
        for (int r = 0; r < 4; ++r) {
            float y = fmaxf(accs[g][r] + sv[r] * cwf + bf3, 0.f);
            ys3[(size_t)(n0 + kq * 4 + r) * 128 + g * 16 + m] = __float2half(dn[r] * y);
        }
    }
}

// ---------------- BN stats over y = ys * rdis ----------------

template <int FOUT>
__global__ void k_stats(const __half* __restrict__ ys, const float* __restrict__ rdis,
                        float* __restrict__ stats) {
    constexpr int GP = 256 / FOUT;
    int f = threadIdx.x % FOUT, g = threadIdx.x / FOUT;
    float s = 0.f, s2 = 0.f;
    for (int n = blockIdx.x * GP + g; n < N_NODES; n += gridDim.x * GP) {
        float v = __half2float(ys[(size_t)n * FOUT + f]) * rdis[n];
        s += v;
        s2 += v * v;
    }
    __shared__ float ls[256], ls2[256];
    ls[threadIdx.x] = s;
    ls2[threadIdx.x] = s2;
    __syncthreads();
    if (g == 0) {
        for (int gg = 1; gg < GP; ++gg) {
            s += ls[gg * FOUT + f];
            s2 += ls2[gg * FOUT + f];
        }
        atomicAdd(&stats[f], s);
        atomicAdd(&stats[FOUT + f], s2);
    }
}

// ---------------- pooling: segment-parallel max/min (y >= 0 -> int-bit compare) ----------------

__global__ void k_pool1(const __half* __restrict__ ys3, const float* __restrict__ rdis,
                        const int* __restrict__ batch, int* __restrict__ gmax,
                        int* __restrict__ gmin) {
    __shared__ int sb[LSEG];
    __shared__ float sr[LSEG];
    int n0 = blockIdx.x * LSEG;
    int n1 = min(n0 + LSEG, N_NODES);
    int L = n1 - n0;
    int f = threadIdx.x;    // 128 threads = feature
    for (int i = f; i < L; i += 128) { sb[i] = batch[n0 + i]; sr[i] = rdis[n0 + i]; }
    __syncthreads();
    if (L <= 0) return;
    int cg = sb[0];
    int mx = 0;                 // y >= 0, so 0-bits is the max identity
    int mn = 0x7F800000;        // +INF bits
    for (int i = 0; i < L; ++i) {
        int g = sb[i];
        if (g != cg) {
            atomicMax(&gmax[cg * 128 + f], mx);
            atomicMin(&gmin[cg * 128 + f], mn);
            cg = g; mx = 0; mn = 0x7F800000;
        }
        float v = __half2float(ys3[(size_t)(n0 + i) * 128 + f]) * sr[i];
        int b = __float_as_int(v);
        mx = max(mx, b);
        mn = min(mn, b);
    }
    atomicMax(&gmax[cg * 128 + f], mx);
    atomicMin(&gmin[cg * 128 + f], mn);
}

// ---------------- fused bn-affine + head + log_softmax ----------------

__device__ __forceinline__ int lower_bound_dev(const int* __restrict__ a, int val) {
    int lo = 0, hi = N_NODES;
    while (lo < hi) {
        int mid = (lo + hi) >> 1;
        if (a[mid] < val) lo = mid + 1; else hi = mid;
    }
    return lo;
}

__global__ void k_poolhead(const int* __restrict__ gmax, const int* __restrict__ gmin,
                           const int* __restrict__ batch, const float* __restrict__ stats,
                           const float* __restrict__ gamma, const float* __restrict__ beta,
                           const float* __restrict__ Wl, const float* __restrict__ bl,
                           float* __restrict__ out) {
    int g = blockIdx.x;
    int f = threadIdx.x;    // 128
    float inv_n = 1.0f / (float)N_NODES;
    float m = stats[f] * inv_n;
    float var = stats[128 + f] * inv_n - m * m;
    float a = gamma[f] * rsqrtf(var + BN_EPS);
    float c = beta[f] - m * a;
    int s = lower_bound_dev(batch, g);
    int e = lower_bound_dev(batch, g + 1);
    float mx = __int_as_float(gmax[g * 128 + f]);
    float mn = __int_as_float(gmin[g * 128 + f]);
    float r;
    if (e > s) r = (a >= 0.f) ? (a * mx + c) : (a * mn + c);
    else r = -INFINITY;
    __shared__ float l[3][128];
    l[0][f] = r * Wl[f * 3 + 0];
    l[1][f] = r * Wl[f * 3 + 1];
    l[2][f] = r * Wl[f * 3 + 2];
    __syncthreads();
    for (int st = 64; st > 0; st >>= 1) {
        if (f < st) {
            l[0][f] += l[0][f + st];
            l[1][f] += l[1][f + st];
            l[2][f] += l[2][f + st];
        }
        __syncthreads();
    }
    if (f == 0) {
        float l0 = l[0][0] + bl[0], l1 = l[1][0] + bl[1], l2 = l[2][0] + bl[2];
        float mxl = fmaxf(l0, fmaxf(l1, l2));
        float lse = mxl + logf(expf(l0 - mxl) + expf(l1 - mxl) + expf(l2 - mxl));
        out[g * 3 + 0] = l0 - lse;
        out[g * 3 + 1] = l1 - lse;
        out[g * 3 + 2] = l2 - lse;
    }
}

// ---------------- launch ----------------

extern "C" void kernel_launch(void* const* d_in, const int* in_sizes, int n_in,
                              void* d_out, int out_size, void* d_ws, size_t ws_size,
                              hipStream_t stream) {
    const float* x   = (const float*)d_in[0];
    const int* ei    = (const int*)d_in[1];
    const int* src   = ei;
    const int* dst   = ei + N_EDGES;
    const int* batch = (const int*)d_in[2];
    const float *W1 = (const float*)d_in[3],  *b1 = (const float*)d_in[4];
    const float *g1 = (const float*)d_in[5],  *be1 = (const float*)d_in[6];
    const float *W2 = (const float*)d_in[7],  *b2 = (const float*)d_in[8];
    const float *g2 = (const float*)d_in[9],  *be2 = (const float*)d_in[10];
    const float *W3 = (const float*)d_in[11], *b3 = (const float*)d_in[12];
    const float *g3 = (const float*)d_in[13], *be3 = (const float*)d_in[14];
    const float *Wl = (const float*)d_in[15], *bl = (const float*)d_in[16];
    float* out = (float*)d_out;

    // workspace carve (4-byte words)
    int* base = (int*)d_ws;
    size_t o = 0;
    float* stats1 = (float*)(base + o); o += 256;
    float* stats2 = (float*)(base + o); o += 256;
    float* stats3 = (float*)(base + o); o += 256;
    int* gmax     = base + o; o += (size_t)N_GRAPHS * 128;
    size_t zero_words = o;                         // zeroed region
    int* gmin     = base + o; o += (size_t)N_GRAPHS * 128;   // memset 0x7F
    int* bbase    = base + o; o += 392;
    int* ghist    = base + o; o += 392;
    int* hists    = base + o; o += ((size_t)NBIN * NCHUNK + 3) & ~3ULL;
    float* W2p    = (float*)(base + o); o += 256;
    float* cw2    = (float*)(base + o); o += 32;
    __half* wfrag = (__half*)(base + o); o += 2048;
    float* cw3    = (float*)(base + o); o += 128;
    int* offs     = base + o; o += 100004;
    int* store    = base + o; o += N_EDGES;
    int* csr      = base + o; o += N_EDGES;
    float* dis    = (float*)(base + o); o += N_NODES;
    float* rdis   = (float*)(base + o); o += N_NODES;
    float* svec   = (float*)(base + o); o += N_NODES;
    __half* ys1   = (__half*)(base + o); o += (size_t)(N_NODES + 1) * 4;
    __half* ys2   = (__half*)(base + o); o += (size_t)(N_NODES + 1) * 16;
    __half* u2    = (__half*)(base + o); o += (size_t)N_NODES * 16;
    __half* ys3   = (__half*)(base + o); o += (size_t)N_NODES * 64;
    if (ws_size < o * 4) return;

    const int TB = 256;
    const int gridAgg = (N_NODES + 3) / 4;

    hipMemsetAsync(base, 0, zero_words * 4, stream);
    hipMemsetAsync(gmin, 0x7F, (size_t)N_GRAPHS * 128 * 4, stream);

    // CSR build
    k_hist2<<<NCHUNK, TB, 0, stream>>>(dst, hists);
    k_scan2<<<NBIN, 64, 0, stream>>>(hists, ghist);
    k_binscan<<<1, 512, 0, stream>>>(ghist, bbase, offs);
    k_scatter<<<NCHUNK, TB, 0, stream>>>(src, dst, bbase, hists, store);
    k_csr_build<<<NBIN, 256, 0, stream>>>(bbase, store, offs, dis, rdis, csr);

    // layer 1
    k_agg1<<<gridAgg, TB, 0, stream>>>(x, offs, csr, dis, W1, b1, svec, ys1);
    k_stats<8><<<256, 256, 0, stream>>>(ys1, rdis, stats1);
    k_prep2<<<1, 256, 0, stream>>>(stats1, g1, be1, W2, W2p, cw2);

    // layer 2
    k_agg2<<<gridAgg, TB, 0, stream>>>(ys1, offs, csr, dis, svec, W2p, cw2, b2, ys2);
    k_stats<32><<<256, 256, 0, stream>>>(ys2, rdis, stats2);
    k_prep3<<<1, 512, 0, stream>>>(stats2, g2, be2, W3, wfrag, cw3, ys2);

    // layer 3
    k_agg3<<<gridAgg, TB, 0, stream>>>(ys2, offs, csr, dis, u2);
    k_mm_mfma<<<(N_NODES + 63) / 64, 256, 0, stream>>>(u2, wfrag, cw3, b3, svec, dis, ys3);
    k_stats<128><<<256, 256, 0, stream>>>(ys3, rdis, stats3);

    // pool + head
    k_pool1<<<NSEGB, 128, 0, stream>>>(ys3, rdis, batch, gmax, gmin);
    k_poolhead<<<N_GRAPHS, 128, 0, stream>>>(gmax, gmin, batch, stats3, g3, be3, Wl, bl, out);
}

// Round 9
// 463.391 us; speedup vs baseline: 3.5671x; 1.0601x over previous
//
#include <hip/hip_runtime.h>
#include <hip/hip_bf16.h>
#include <hip/hip_fp16.h>
#include <math.h>

#define N_NODES 100000
#define N_EDGES 3200000
#define N_GRAPHS 512
#define BN_EPS 1e-5f
#define NBIN ((N_NODES + 255) / 256)            // 391 bins of 256 nodes
#define CHUNK 8192                              // edges per chunk block
#define NCHUNK ((N_EDGES + CHUNK - 1) / CHUNK)  // 391
#define LSEG 98
#define NSEGB ((N_NODES + LSEG - 1) / LSEG)     // 1021 pool segments

typedef _Float16 half8_t __attribute__((ext_vector_type(8)));
typedef float float4_t __attribute__((ext_vector_type(4)));

struct alignas(8) h4 { __half2 a, b; };
struct alignas(16) h8s { __half2 h[4]; };

// ---------------- CSR build: single-scatter radix ----------------

__global__ void k_hist2(const int* __restrict__ dst, int* __restrict__ hists) {
    __shared__ int h[NBIN];
    for (int i = threadIdx.x; i < NBIN; i += blockDim.x) h[i] = 0;
    __syncthreads();
    int e0 = blockIdx.x * CHUNK;
    int e1 = min(e0 + CHUNK, N_EDGES);
    for (int e = e0 + threadIdx.x; e < e1; e += blockDim.x)
        atomicAdd(&h[dst[e] >> 8], 1);
    __syncthreads();
    for (int i = threadIdx.x; i < NBIN; i += blockDim.x)
        hists[i * NCHUNK + blockIdx.x] = h[i];
}

__global__ void k_scan2(int* __restrict__ hists, int* __restrict__ ghist) {
    int b = blockIdx.x;
    int lane = threadIdx.x;   // 64 threads
    int carry = 0;
    int base = b * NCHUNK;
    for (int c0 = 0; c0 < NCHUNK; c0 += 64) {
        int c = c0 + lane;
        int v = (c < NCHUNK) ? hists[base + c] : 0;
        int inc = v;
#pragma unroll
        for (int off = 1; off < 64; off <<= 1) {
            int u = __shfl_up(inc, off, 64);
            if (lane >= off) inc += u;
        }
        if (c < NCHUNK) hists[base + c] = inc - v + carry;
        carry += __shfl(inc, 63, 64);
    }
    if (lane == 0) ghist[b] = carry;
}

__global__ void k_binscan(const int* __restrict__ ghist, int* __restrict__ bbase,
                          int* __restrict__ offs) {
    __shared__ int sd[512];
    int t = threadIdx.x;
    int v = (t < NBIN) ? ghist[t] : 0;
    sd[t] = v;
    __syncthreads();
    for (int off = 1; off < 512; off <<= 1) {
        int u = (t >= off) ? sd[t - off] : 0;
        __syncthreads();
        sd[t] += u;
        __syncthreads();
    }
    if (t < NBIN) bbase[t] = sd[t] - v;
    if (t == 0) { bbase[NBIN] = N_EDGES; offs[N_NODES] = N_EDGES; }
}

__global__ void k_scatter(const int* __restrict__ src, const int* __restrict__ dst,
                          const int* __restrict__ bbase, const int* __restrict__ hists,
                          int* __restrict__ store) {
    __shared__ int cur[NBIN];
    for (int i = threadIdx.x; i < NBIN; i += blockDim.x)
        cur[i] = bbase[i] + hists[i * NCHUNK + blockIdx.x];
    __syncthreads();
    int e0 = blockIdx.x * CHUNK;
    int e1 = min(e0 + CHUNK, N_EDGES);
    for (int e = e0 + threadIdx.x; e < e1; e += blockDim.x) {
        int d = dst[e];
        int b = d >> 8;
        int pos = atomicAdd(&cur[b], 1);
        store[pos] = (src[e] << 8) | (d & 255);
    }
}

__global__ void k_csr_build(const int* __restrict__ bbase, const int* __restrict__ store,
                            const float* __restrict__ x, int* __restrict__ offs,
                            float* __restrict__ dis, float* __restrict__ rdis,
                            float4* __restrict__ xd, int* __restrict__ csr) {
    __shared__ int cnt[256], cur[256], wsum[4];
    int b = blockIdx.x;
    int n0 = b << 8;
    int nn = min(256, N_NODES - n0);
    int e0 = bbase[b], e1 = bbase[b + 1];
    int t = threadIdx.x;
    cnt[t] = 0;
    __syncthreads();
    for (int e = e0 + t; e < e1; e += 256) atomicAdd(&cnt[store[e] & 255], 1);
    __syncthreads();
    int c = cnt[t];
    int inc = c;
    int lane = t & 63, wid = t >> 6;
#pragma unroll
    for (int off = 1; off < 64; off <<= 1) {
        int u = __shfl_up(inc, off, 64);
        if (lane >= off) inc += u;
    }
    if (lane == 63) wsum[wid] = inc;
    __syncthreads();
    int wo = 0;
    for (int w = 0; w < wid; ++w) wo += wsum[w];
    int ex = inc - c + wo;
    cur[t] = ex;
    if (t < nn) {
        int n = n0 + t;
        offs[n] = e0 + ex;
        float dn = rsqrtf(1.0f + (float)c);
        dis[n] = dn;
        rdis[n] = sqrtf(1.0f + (float)c);
        float2 xv = *(const float2*)(x + 2 * (size_t)n);
        xd[n] = make_float4(dn * xv.x, dn * xv.y, dn, 0.f);
    }
    if (n0 + t == N_NODES) xd[N_NODES] = make_float4(0.f, 0.f, 0.f, 0.f);
    __syncthreads();
    for (int e = e0 + t; e < e1; e += 256) {
        int p = store[e];
        int pos = e0 + atomicAdd(&cur[p & 255], 1);
        csr[pos] = p >> 8;
    }
}

// ---------------- layer 1: aggregate xd (dis*x, dis) + fused 2->8 mm + relu ----------------

__global__ void k_agg1(const float4* __restrict__ xd, const int* __restrict__ offs,
                       const int* __restrict__ csr, const float* __restrict__ W1,
                       const float* __restrict__ b1, float* __restrict__ svec,
                       __half* __restrict__ ys1) {
    __shared__ float sW[16], sb[8];
    int t = threadIdx.x;
    if (t < 16) sW[t] = W1[t];
    if (t < 8) sb[t] = b1[t];
    __syncthreads();
    int wave = t >> 6, lane = t & 63;
    int node = blockIdx.x * 4 + wave;
    if (node >= N_NODES) return;
    int e0 = offs[node], e1 = offs[node + 1];
    float ax = 0.f, ay = 0.f, as = 0.f;
    for (int e = e0 + lane; e < e1; e += 128) {
        int s0 = csr[e];
        int s1 = (e + 64 < e1) ? csr[e + 64] : N_NODES;
        float4 v0 = xd[s0];
        float4 v1 = xd[s1];
        ax += v0.x + v1.x;
        ay += v0.y + v1.y;
        as += v0.z + v1.z;
    }
#pragma unroll
    for (int off = 1; off < 64; off <<= 1) {
        ax += __shfl_xor(ax, off, 64);
        ay += __shfl_xor(ay, off, 64);
        as += __shfl_xor(as, off, 64);
    }
    if (lane == 0) {
        float4 xn = xd[node];
        float dn = xn.z;
        float u0x = dn * (ax + xn.x);
        float u0y = dn * (ay + xn.y);
        svec[node] = dn * (as + xn.z);
        float y[8];
#pragma unroll
        for (int f = 0; f < 8; ++f)
            y[f] = dn * fmaxf(u0x * sW[f] + u0y * sW[8 + f] + sb[f], 0.f);
        h8s o;
#pragma unroll
        for (int q = 0; q < 4; ++q) o.h[q] = __floats2half2_rn(y[2 * q], y[2 * q + 1]);
        *(h8s*)(ys1 + (size_t)node * 8) = o;
    }
}

// ---------------- prep2: bn fold into W2; zero row ys1[N] ----------------

__global__ void k_prep2(const float* __restrict__ stats, const float* __restrict__ gamma,
                        const float* __restrict__ beta, const float* __restrict__ W2,
                        float* __restrict__ W2p, float* __restrict__ cw2,
                        __half* __restrict__ ys1) {
    __shared__ float a1[8], c1[8];
    int t = threadIdx.x;   // 256
    if (t < 8) {
        float inv_n = 1.0f / (float)N_NODES;
        float m = stats[t] * inv_n;
        float v = stats[8 + t] * inv_n - m * m;
        float a = gamma[t] * rsqrtf(v + BN_EPS);
        a1[t] = a;
        c1[t] = beta[t] - m * a;
    }
    __syncthreads();
    W2p[t] = a1[t >> 5] * W2[t];    // 8x32 = 256
    if (t < 32) {
        float cb = 0.f;
#pragma unroll
        for (int i = 0; i < 8; ++i) cb += c1[i] * W2[i * 32 + t];
        cw2[t] = cb;
    }
    if (t == 128) *(int4*)(ys1 + (size_t)N_NODES * 8) = make_int4(0, 0, 0, 0);
}

// ---------------- layer 2: aggregate ys1 (width 8), fused 8->32 mm + relu ----------------
// lane = (edge-group 0..31, chunk 0..1); 5-level butterfly; shfl-broadcast epilogue

__global__ void k_agg2(const __half* __restrict__ ys1, const int* __restrict__ offs,
                       const int* __restrict__ csr, const float* __restrict__ dis,
                       const float* __restrict__ svec, const float* __restrict__ W2p,
                       const float* __restrict__ cw2, const float* __restrict__ b2,
                       __half* __restrict__ ys2) {
    __shared__ float sW[256], sC[32], sB[32];
    int t = threadIdx.x;
    sW[t] = W2p[t];
    if (t < 32) { sC[t] = cw2[t]; sB[t] = b2[t]; }
    __syncthreads();
    int wave = t >> 6, lane = t & 63;
    int node = blockIdx.x * 4 + wave;
    if (node >= N_NODES) return;
    int chunk = lane & 1, eg = lane >> 1;
    int e0 = offs[node], e1 = offs[node + 1];
    float a0 = 0.f, a1 = 0.f, a2 = 0.f, a3 = 0.f;
    const __half* hp = ys1 + chunk * 4;
    for (int e = e0 + eg; e < e1; e += 64) {
        int s0 = csr[e];
        int s1 = (e + 32 < e1) ? csr[e + 32] : N_NODES;
        h4 v0 = *(const h4*)(hp + (size_t)s0 * 8);
        h4 v1 = *(const h4*)(hp + (size_t)s1 * 8);
        a0 += __low2float(v0.a) + __low2float(v1.a);
        a1 += __high2float(v0.a) + __high2float(v1.a);
        a2 += __low2float(v0.b) + __low2float(v1.b);
        a3 += __high2float(v0.b) + __high2float(v1.b);
    }
    if (eg == 0) {   // self-loop: lane 0 covers chunk 0, lane 1 covers chunk 1
        h4 v = *(const h4*)(hp + (size_t)node * 8);
        a0 += __low2float(v.a);
        a1 += __high2float(v.a);
        a2 += __low2float(v.b);
        a3 += __high2float(v.b);
    }
#pragma unroll
    for (int off = 2; off < 64; off <<= 1) {
        a0 += __shfl_xor(a0, off, 64);
        a1 += __shfl_xor(a1, off, 64);
        a2 += __shfl_xor(a2, off, 64);
        a3 += __shfl_xor(a3, off, 64);
    }
    float u[8];
    u[0] = __shfl(a0, 0, 64); u[1] = __shfl(a1, 0, 64);
    u[2] = __shfl(a2, 0, 64); u[3] = __shfl(a3, 0, 64);
    u[4] = __shfl(a0, 1, 64); u[5] = __shfl(a1, 1, 64);
    u[6] = __shfl(a2, 1, 64); u[7] = __shfl(a3, 1, 64);
    if (lane < 32) {
        float dn = dis[node];
        float conv = sB[lane] + svec[node] * sC[lane];
#pragma unroll
        for (int i = 0; i < 8; ++i) conv += (dn * u[i]) * sW[i * 32 + lane];
        ys2[(size_t)node * 32 + lane] = __float2half(dn * fmaxf(conv, 0.f));
    }
}

// ---------------- prep3 ----------------

__global__ void k_prep3(const float* __restrict__ stats, const float* __restrict__ gamma,
                        const float* __restrict__ beta, const float* __restrict__ W3,
                        __half* __restrict__ wfrag, float* __restrict__ cw3,
                        __half* __restrict__ ys2) {
    __shared__ float a2[32], c2[32];
    int t = threadIdx.x;   // 512
    if (t < 32) {
        float inv_n = 1.0f / (float)N_NODES;
        float m = stats[t] * inv_n;
        float v = stats[32 + t] * inv_n - m * m;
        float a = gamma[t] * rsqrtf(v + BN_EPS);
        a2[t] = a;
        c2[t] = beta[t] - m * a;
    }
    __syncthreads();
    {
        int g = t >> 6, kq = (t >> 4) & 3, c = t & 15;
#pragma unroll
        for (int j = 0; j < 8; ++j) {
            int k = kq * 8 + j;
            wfrag[(size_t)t * 8 + j] = __float2half(a2[k] * W3[k * 128 + g * 16 + c]);
        }
    }
    if (t < 128) {
        float cb = 0.f;
#pragma unroll
        for (int k = 0; k < 32; ++k) cb += c2[k] * W3[k * 128 + t];
        cw3[t] = cb;
    }
    if (t >= 480 && t < 496)
        ((__half2*)(ys2 + (size_t)N_NODES * 32))[t - 480] =
            __half2{__float2half(0.f), __float2half(0.f)};
}

// ---------------- layer 3 aggregation: ys2 (width 32) -> u2 ----------------

__global__ void k_agg3(const __half* __restrict__ ys2, const int* __restrict__ offs,
                       const int* __restrict__ csr, const float* __restrict__ dis,
                       __half* __restrict__ u2) {
    int wave = threadIdx.x >> 6;
    int lane = threadIdx.x & 63;
    int node = blockIdx.x * 4 + wave;
    if (node >= N_NODES) return;
    int chunk = lane & 7;
    int eg = lane >> 3;
    int e0 = offs[node], e1 = offs[node + 1];
    float ax = 0.f, ay = 0.f, az = 0.f, aw = 0.f;
    const __half* hp = ys2 + (size_t)chunk * 4;
    for (int e = e0 + eg; e < e1; e += 32) {
        int s0 = csr[e];
        int s1 = (e + 8 < e1) ? csr[e + 8] : N_NODES;
        int s2 = (e + 16 < e1) ? csr[e + 16] : N_NODES;
        int s3 = (e + 24 < e1) ? csr[e + 24] : N_NODES;
        h4 v0 = *(const h4*)(hp + (size_t)s0 * 32);
        h4 v1 = *(const h4*)(hp + (size_t)s1 * 32);
        h4 v2 = *(const h4*)(hp + (size_t)s2 * 32);
        h4 v3 = *(const h4*)(hp + (size_t)s3 * 32);
        ax += __low2float(v0.a) + __low2float(v1.a) + __low2float(v2.a) + __low2float(v3.a);
        ay += __high2float(v0.a) + __high2float(v1.a) + __high2float(v2.a) + __high2float(v3.a);
        az += __low2float(v0.b) + __low2float(v1.b) + __low2float(v2.b) + __low2float(v3.b);
        aw += __high2float(v0.b) + __high2float(v1.b) + __high2float(v2.b) + __high2float(v3.b);
    }
    if (eg == 0) {
        h4 v = *(const h4*)(hp + (size_t)node * 32);
        ax += __low2float(v.a);
        ay += __high2float(v.a);
        az += __low2float(v.b);
        aw += __high2float(v.b);
    }
#pragma unroll
    for (int off = 8; off < 64; off <<= 1) {
        ax += __shfl_xor(ax, off, 64);
        ay += __shfl_xor(ay, off, 64);
        az += __shfl_xor(az, off, 64);
        aw += __shfl_xor(aw, off, 64);
    }
    if (lane < 8) {
        float dn = dis[node];
        h4 o;
        o.a = __floats2half2_rn(dn * ax, dn * ay);
        o.b = __floats2half2_rn(dn * az, dn * aw);
        *(h4*)(u2 + (size_t)node * 32 + chunk * 4) = o;
    }
}

// ---------------- layer 3 transform via MFMA ----------------

__global__ void k_mm_mfma(const __half* __restrict__ u2, const __half* __restrict__ wfrag,
                          const float* __restrict__ cw3, const float* __restrict__ b3,
                          const float* __restrict__ svec, const float* __restrict__ dis,
                          __half* __restrict__ ys3) {
    int wave = threadIdx.x >> 6;
    int lane = threadIdx.x & 63;
    int n0 = (blockIdx.x * 4 + wave) * 16;
    if (n0 >= N_NODES) return;
    int m = lane & 15;
    int kq = lane >> 4;

    half8_t af = *(const half8_t*)(u2 + (size_t)(n0 + m) * 32 + kq * 8);

    float4_t accs[8];
#pragma unroll
    for (int g = 0; g < 8; ++g) {
        float4_t acc = {0.f, 0.f, 0.f, 0.f};
        half8_t bf = *(const half8_t*)(wfrag + (size_t)((g * 4 + kq) * 16 + m) * 8);
        accs[g] = __builtin_amdgcn_mfma_f32_16x16x32_f16(af, bf, acc, 0, 0, 0);
    }
    float sv[4], dn[4];
#pragma unroll
    for (int r = 0; r < 4; ++r) {
        sv[r] = svec[n0 + kq * 4 + r];
        dn[r] = dis[n0 + kq * 4 + r];
    }
#pragma unroll
    for (int g = 0; g < 8; ++g) {
        float cwf = cw3[g * 16 + m];
        float bf3 = b3[g * 16 + m];
#pragma unroll
        for (int r = 0; r < 4; ++r) {
            float y = fmaxf(accs[g][r] + sv[r] * cwf + bf3, 0.f);
            ys3[(size_t)(n0 + kq * 4 + r) * 128 + g * 16 + m] = __float2half(dn[r] * y);
        }
    }
}

// ---------------- BN stats over y = ys * rdis ----------------

template <int FOUT>
__global__ void k_stats(const __half* __restrict__ ys, const float* __restrict__ rdis,
                        float* __restrict__ stats) {
    constexpr int GP = 256 / FOUT;
    int f = threadIdx.x % FOUT, g = threadIdx.x / FOUT;
    float s = 0.f, s2 = 0.f;
    for (int n = blockIdx.x * GP + g; n < N_NODES; n += gridDim.x * GP) {
        float v = __half2float(ys[(size_t)n * FOUT + f]) * rdis[n];
        s += v;
        s2 += v * v;
    }
    __shared__ float ls[256], ls2[256];
    ls[threadIdx.x] = s;
    ls2[threadIdx.x] = s2;
    __syncthreads();
    if (g == 0) {
        for (int gg = 1; gg < GP; ++gg) {
            s += ls[gg * FOUT + f];
            s2 += ls2[gg * FOUT + f];
        }
        atomicAdd(&stats[f], s);
        atomicAdd(&stats[FOUT + f], s2);
    }
}

// ---------------- pooling: segment-parallel max/min ----------------

__global__ void k_pool1(const __half* __restrict__ ys3, const float* __restrict__ rdis,
                        const int* __restrict__ batch, int* __restrict__ gmax,
                        int* __restrict__ gmin) {
    __shared__ int sb[LSEG];
    __shared__ float sr[LSEG];
    int n0 = blockIdx.x * LSEG;
    int n1 = min(n0 + LSEG, N_NODES);
    int L = n1 - n0;
    int f = threadIdx.x;    // 128 threads = feature
    for (int i = f; i < L; i += 128) { sb[i] = batch[n0 + i]; sr[i] = rdis[n0 + i]; }
    __syncthreads();
    if (L <= 0) return;
    int cg = sb[0];
    int mx = 0;
    int mn = 0x7F800000;
    for (int i = 0; i < L; ++i) {
        int g = sb[i];
        if (g != cg) {
            atomicMax(&gmax[cg * 128 + f], mx);
            atomicMin(&gmin[cg * 128 + f], mn);
            cg = g; mx = 0; mn = 0x7F800000;
        }
        float v = __half2float(ys3[(size_t)(n0 + i) * 128 + f]) * sr[i];
        int b = __float_as_int(v);
        mx = max(mx, b);
        mn = min(mn, b);
    }
    atomicMax(&gmax[cg * 128 + f], mx);
    atomicMin(&gmin[cg * 128 + f], mn);
}

// ---------------- fused bn-affine + head + log_softmax ----------------

__device__ __forceinline__ int lower_bound_dev(const int* __restrict__ a, int val) {
    int lo = 0, hi = N_NODES;
    while (lo < hi) {
        int mid = (lo + hi) >> 1;
        if (a[mid] < val) lo = mid + 1; else hi = mid;
    }
    return lo;
}

__global__ void k_poolhead(const int* __restrict__ gmax, const int* __restrict__ gmin,
                           const int* __restrict__ batch, const float* __restrict__ stats,
                           const float* __restrict__ gamma, const float* __restrict__ beta,
                           const float* __restrict__ Wl, const float* __restrict__ bl,
                           float* __restrict__ out) {
    int g = blockIdx.x;
    int f = threadIdx.x;    // 128
    float inv_n = 1.0f / (float)N_NODES;
    float m = stats[f] * inv_n;
    float var = stats[128 + f] * inv_n - m * m;
    float a = gamma[f] * rsqrtf(var + BN_EPS);
    float c = beta[f] - m * a;
    int s = lower_bound_dev(batch, g);
    int e = lower_bound_dev(batch, g + 1);
    float mx = __int_as_float(gmax[g * 128 + f]);
    float mn = __int_as_float(gmin[g * 128 + f]);
    float r;
    if (e > s) r = (a >= 0.f) ? (a * mx + c) : (a * mn + c);
    else r = -INFINITY;
    __shared__ float l[3][128];
    l[0][f] = r * Wl[f * 3 + 0];
    l[1][f] = r * Wl[f * 3 + 1];
    l[2][f] = r * Wl[f * 3 + 2];
    __syncthreads();
    for (int st = 64; st > 0; st >>= 1) {
        if (f < st) {
            l[0][f] += l[0][f + st];
            l[1][f] += l[1][f + st];
            l[2][f] += l[2][f + st];
        }
        __syncthreads();
    }
    if (f == 0) {
        float l0 = l[0][0] + bl[0], l1 = l[1][0] + bl[1], l2 = l[2][0] + bl[2];
        float mxl = fmaxf(l0, fmaxf(l1, l2));
        float lse = mxl + logf(expf(l0 - mxl) + expf(l1 - mxl) + expf(l2 - mxl));
        out[g * 3 + 0] = l0 - lse;
        out[g * 3 + 1] = l1 - lse;
        out[g * 3 + 2] = l2 - lse;
    }
}

// ---------------- launch ----------------

extern "C" void kernel_launch(void* const* d_in, const int* in_sizes, int n_in,
                              void* d_out, int out_size, void* d_ws, size_t ws_size,
                              hipStream_t stream) {
    const float* x   = (const float*)d_in[0];
    const int* ei    = (const int*)d_in[1];
    const int* src   = ei;
    const int* dst   = ei + N_EDGES;
    const int* batch = (const int*)d_in[2];
    const float *W1 = (const float*)d_in[3],  *b1 = (const float*)d_in[4];
    const float *g1 = (const float*)d_in[5],  *be1 = (const float*)d_in[6];
    const float *W2 = (const float*)d_in[7],  *b2 = (const float*)d_in[8];
    const float *g2 = (const float*)d_in[9],  *be2 = (const float*)d_in[10];
    const float *W3 = (const float*)d_in[11], *b3 = (const float*)d_in[12];
    const float *g3 = (const float*)d_in[13], *be3 = (const float*)d_in[14];
    const float *Wl = (const float*)d_in[15], *bl = (const float*)d_in[16];
    float* out = (float*)d_out;

    // workspace carve (4-byte words)
    int* base = (int*)d_ws;
    size_t o = 0;
    float* stats1 = (float*)(base + o); o += 256;
    float* stats2 = (float*)(base + o); o += 256;
    float* stats3 = (float*)(base + o); o += 256;
    int* gmax     = base + o; o += (size_t)N_GRAPHS * 128;
    size_t zero_words = o;                         // zeroed region
    int* gmin     = base + o; o += (size_t)N_GRAPHS * 128;   // memset 0x7F
    int* bbase    = base + o; o += 392;
    int* ghist    = base + o; o += 392;
    int* hists    = base + o; o += ((size_t)NBIN * NCHUNK + 3) & ~3ULL;
    float* W2p    = (float*)(base + o); o += 256;
    float* cw2    = (float*)(base + o); o += 32;
    __half* wfrag = (__half*)(base + o); o += 2048;
    float* cw3    = (float*)(base + o); o += 128;
    int* offs     = base + o; o += 100004;
    int* store    = base + o; o += N_EDGES;
    int* csr      = base + o; o += N_EDGES;
    float* dis    = (float*)(base + o); o += N_NODES;
    float* rdis   = (float*)(base + o); o += N_NODES;
    float* svec   = (float*)(base + o); o += N_NODES;
    float4* xd    = (float4*)(base + o); o += (size_t)(N_NODES + 1) * 4;
    __half* ys1   = (__half*)(base + o); o += (size_t)(N_NODES + 1) * 4;
    __half* ys2   = (__half*)(base + o); o += (size_t)(N_NODES + 1) * 16;
    __half* u2    = (__half*)(base + o); o += (size_t)N_NODES * 16;
    __half* ys3   = (__half*)(base + o); o += (size_t)N_NODES * 64;
    if (ws_size < o * 4) return;

    const int TB = 256;
    const int gridAgg = (N_NODES + 3) / 4;

    hipMemsetAsync(base, 0, zero_words * 4, stream);
    hipMemsetAsync(gmin, 0x7F, (size_t)N_GRAPHS * 128 * 4, stream);

    // CSR build
    k_hist2<<<NCHUNK, TB, 0, stream>>>(dst, hists);
    k_scan2<<<NBIN, 64, 0, stream>>>(hists, ghist);
    k_binscan<<<1, 512, 0, stream>>>(ghist, bbase, offs);
    k_scatter<<<NCHUNK, TB, 0, stream>>>(src, dst, bbase, hists, store);
    k_csr_build<<<NBIN, 256, 0, stream>>>(bbase, store, x, offs, dis, rdis, xd, csr);

    // layer 1
    k_agg1<<<gridAgg, TB, 0, stream>>>(xd, offs, csr, W1, b1, svec, ys1);
    k_stats<8><<<256, 256, 0, stream>>>(ys1, rdis, stats1);
    k_prep2<<<1, 256, 0, stream>>>(stats1, g1, be1, W2, W2p, cw2, ys1);

    // layer 2
    k_agg2<<<gridAgg, TB, 0, stream>>>(ys1, offs, csr, dis, svec, W2p, cw2, b2, ys2);
    k_stats<32><<<256, 256, 0, stream>>>(ys2, rdis, stats2);
    k_prep3<<<1, 512, 0, stream>>>(stats2, g2, be2, W3, wfrag, cw3, ys2);

    // layer 3
    k_agg3<<<gridAgg, TB, 0, stream>>>(ys2, offs, csr, dis, u2);
    k_mm_mfma<<<(N_NODES + 63) / 64, 256, 0, stream>>>(u2, wfrag, cw3, b3, svec, dis, ys3);
    k_stats<128><<<256, 256, 0, stream>>>(ys3, rdis, stats3);

    // pool + head
    k_pool1<<<NSEGB, 128, 0, stream>>>(ys3, rdis, batch, gmax, gmin);
    k_poolhead<<<N_GRAPHS, 128, 0, stream>>>(gmax, gmin, batch, stats3, g3, be3, Wl, bl, out);
}

// Round 10
// 413.980 us; speedup vs baseline: 3.9929x; 1.1194x over previous
//
#include <hip/hip_runtime.h>
#include <hip/hip_bf16.h>
#include <hip/hip_fp16.h>
#include <math.h>

#define N_NODES 100000
#define N_EDGES 3200000
#define N_GRAPHS 512
#define BN_EPS 1e-5f
#define NBIN ((N_NODES + 255) / 256)            // 391 bins of 256 nodes
#define CHUNK 8192                              // edges per chunk block
#define NCHUNK ((N_EDGES + CHUNK - 1) / CHUNK)  // 391
#define LSEG 98
#define NSEGB ((N_NODES + LSEG - 1) / LSEG)     // 1021 pool segments
#define NSTATB ((N_NODES + 127) / 128)          // 782 stats slabs

typedef _Float16 half8_t __attribute__((ext_vector_type(8)));
typedef float float4_t __attribute__((ext_vector_type(4)));

struct alignas(8) h4 { __half2 a, b; };
struct alignas(16) h8s { __half2 h[4]; };

// ---------------- CSR build: single-scatter radix ----------------

__global__ void k_hist2(const int* __restrict__ dst, int* __restrict__ hists) {
    __shared__ int h[NBIN];
    for (int i = threadIdx.x; i < NBIN; i += blockDim.x) h[i] = 0;
    __syncthreads();
    int e0 = blockIdx.x * CHUNK;
    int e1 = min(e0 + CHUNK, N_EDGES);
    for (int e = e0 + threadIdx.x; e < e1; e += blockDim.x)
        atomicAdd(&h[dst[e] >> 8], 1);
    __syncthreads();
    for (int i = threadIdx.x; i < NBIN; i += blockDim.x)
        hists[i * NCHUNK + blockIdx.x] = h[i];
}

__global__ void k_scan2(int* __restrict__ hists, int* __restrict__ ghist) {
    int b = blockIdx.x;
    int lane = threadIdx.x;   // 64 threads
    int carry = 0;
    int base = b * NCHUNK;
    for (int c0 = 0; c0 < NCHUNK; c0 += 64) {
        int c = c0 + lane;
        int v = (c < NCHUNK) ? hists[base + c] : 0;
        int inc = v;
#pragma unroll
        for (int off = 1; off < 64; off <<= 1) {
            int u = __shfl_up(inc, off, 64);
            if (lane >= off) inc += u;
        }
        if (c < NCHUNK) hists[base + c] = inc - v + carry;
        carry += __shfl(inc, 63, 64);
    }
    if (lane == 0) ghist[b] = carry;
}

__global__ void k_binscan(const int* __restrict__ ghist, int* __restrict__ bbase,
                          int* __restrict__ offs) {
    __shared__ int sd[512];
    int t = threadIdx.x;
    int v = (t < NBIN) ? ghist[t] : 0;
    sd[t] = v;
    __syncthreads();
    for (int off = 1; off < 512; off <<= 1) {
        int u = (t >= off) ? sd[t - off] : 0;
        __syncthreads();
        sd[t] += u;
        __syncthreads();
    }
    if (t < NBIN) bbase[t] = sd[t] - v;
    if (t == 0) { bbase[NBIN] = N_EDGES; offs[N_NODES] = N_EDGES; }
}

__global__ void k_scatter(const int* __restrict__ src, const int* __restrict__ dst,
                          const int* __restrict__ bbase, const int* __restrict__ hists,
                          int* __restrict__ store) {
    __shared__ int cur[NBIN];
    for (int i = threadIdx.x; i < NBIN; i += blockDim.x)
        cur[i] = bbase[i] + hists[i * NCHUNK + blockIdx.x];
    __syncthreads();
    int e0 = blockIdx.x * CHUNK;
    int e1 = min(e0 + CHUNK, N_EDGES);
    for (int e = e0 + threadIdx.x; e < e1; e += blockDim.x) {
        int d = dst[e];
        int b = d >> 8;
        int pos = atomicAdd(&cur[b], 1);
        store[pos] = (src[e] << 8) | (d & 255);
    }
}

__global__ void k_csr_build(const int* __restrict__ bbase, const int* __restrict__ store,
                            const float* __restrict__ x, int* __restrict__ offs,
                            float* __restrict__ dis, float* __restrict__ rdis,
                            float4* __restrict__ xd, int* __restrict__ csr) {
    __shared__ int cnt[256], cur[256], wsum[4];
    int b = blockIdx.x;
    int n0 = b << 8;
    int nn = min(256, N_NODES - n0);
    int e0 = bbase[b], e1 = bbase[b + 1];
    int t = threadIdx.x;
    cnt[t] = 0;
    __syncthreads();
    for (int e = e0 + t; e < e1; e += 256) atomicAdd(&cnt[store[e] & 255], 1);
    __syncthreads();
    int c = cnt[t];
    int inc = c;
    int lane = t & 63, wid = t >> 6;
#pragma unroll
    for (int off = 1; off < 64; off <<= 1) {
        int u = __shfl_up(inc, off, 64);
        if (lane >= off) inc += u;
    }
    if (lane == 63) wsum[wid] = inc;
    __syncthreads();
    int wo = 0;
    for (int w = 0; w < wid; ++w) wo += wsum[w];
    int ex = inc - c + wo;
    cur[t] = ex;
    if (t < nn) {
        int n = n0 + t;
        offs[n] = e0 + ex;
        float dn = rsqrtf(1.0f + (float)c);
        dis[n] = dn;
        rdis[n] = sqrtf(1.0f + (float)c);
        float2 xv = *(const float2*)(x + 2 * (size_t)n);
        xd[n] = make_float4(dn * xv.x, dn * xv.y, dn, 0.f);
    }
    if (n0 + t == N_NODES) xd[N_NODES] = make_float4(0.f, 0.f, 0.f, 0.f);
    __syncthreads();
    for (int e = e0 + t; e < e1; e += 256) {
        int p = store[e];
        int pos = e0 + atomicAdd(&cur[p & 255], 1);
        csr[pos] = p >> 8;
    }
}

// ---------------- layer 1: aggregate xd (dis*x, dis) + fused 2->8 mm + relu ----------------

__global__ void k_agg1(const float4* __restrict__ xd, const int* __restrict__ offs,
                       const int* __restrict__ csr, const float* __restrict__ W1,
                       const float* __restrict__ b1, float* __restrict__ svec,
                       __half* __restrict__ ys1) {
    __shared__ float sW[16], sb[8];
    int t = threadIdx.x;
    if (t < 16) sW[t] = W1[t];
    if (t < 8) sb[t] = b1[t];
    __syncthreads();
    int wave = t >> 6, lane = t & 63;
    int node = blockIdx.x * 4 + wave;
    if (node >= N_NODES) return;
    int e0 = offs[node], e1 = offs[node + 1];
    float ax = 0.f, ay = 0.f, as = 0.f;
    for (int e = e0 + lane; e < e1; e += 128) {
        int s0 = csr[e];
        int s1 = (e + 64 < e1) ? csr[e + 64] : N_NODES;
        float4 v0 = xd[s0];
        float4 v1 = xd[s1];
        ax += v0.x + v1.x;
        ay += v0.y + v1.y;
        as += v0.z + v1.z;
    }
#pragma unroll
    for (int off = 1; off < 64; off <<= 1) {
        ax += __shfl_xor(ax, off, 64);
        ay += __shfl_xor(ay, off, 64);
        as += __shfl_xor(as, off, 64);
    }
    if (lane == 0) {
        float4 xn = xd[node];
        float dn = xn.z;
        float u0x = dn * (ax + xn.x);
        float u0y = dn * (ay + xn.y);
        svec[node] = dn * (as + xn.z);
        float y[8];
#pragma unroll
        for (int f = 0; f < 8; ++f)
            y[f] = dn * fmaxf(u0x * sW[f] + u0y * sW[8 + f] + sb[f], 0.f);
        h8s o;
#pragma unroll
        for (int q = 0; q < 4; ++q) o.h[q] = __floats2half2_rn(y[2 * q], y[2 * q + 1]);
        *(h8s*)(ys1 + (size_t)node * 8) = o;
    }
}

// ---------------- prep2: bn fold into W2; zero row ys1[N] ----------------

__global__ void k_prep2(const float* __restrict__ stats, const float* __restrict__ gamma,
                        const float* __restrict__ beta, const float* __restrict__ W2,
                        float* __restrict__ W2p, float* __restrict__ cw2,
                        __half* __restrict__ ys1) {
    __shared__ float a1[8], c1[8];
    int t = threadIdx.x;   // 256
    if (t < 8) {
        float inv_n = 1.0f / (float)N_NODES;
        float m = stats[t] * inv_n;
        float v = stats[8 + t] * inv_n - m * m;
        float a = gamma[t] * rsqrtf(v + BN_EPS);
        a1[t] = a;
        c1[t] = beta[t] - m * a;
    }
    __syncthreads();
    W2p[t] = a1[t >> 5] * W2[t];    // 8x32 = 256
    if (t < 32) {
        float cb = 0.f;
#pragma unroll
        for (int i = 0; i < 8; ++i) cb += c1[i] * W2[i * 32 + t];
        cw2[t] = cb;
    }
    if (t == 128) *(int4*)(ys1 + (size_t)N_NODES * 8) = make_int4(0, 0, 0, 0);
}

// ---------------- layer 2: aggregate ys1 (width 8), fused 8->32 mm + relu ----------------

__global__ void k_agg2(const __half* __restrict__ ys1, const int* __restrict__ offs,
                       const int* __restrict__ csr, const float* __restrict__ dis,
                       const float* __restrict__ svec, const float* __restrict__ W2p,
                       const float* __restrict__ cw2, const float* __restrict__ b2,
                       __half* __restrict__ ys2) {
    __shared__ float sW[256], sC[32], sB[32];
    int t = threadIdx.x;
    sW[t] = W2p[t];
    if (t < 32) { sC[t] = cw2[t]; sB[t] = b2[t]; }
    __syncthreads();
    int wave = t >> 6, lane = t & 63;
    int node = blockIdx.x * 4 + wave;
    if (node >= N_NODES) return;
    int chunk = lane & 1, eg = lane >> 1;
    int e0 = offs[node], e1 = offs[node + 1];
    float a0 = 0.f, a1 = 0.f, a2 = 0.f, a3 = 0.f;
    const __half* hp = ys1 + chunk * 4;
    for (int e = e0 + eg; e < e1; e += 64) {
        int s0 = csr[e];
        int s1 = (e + 32 < e1) ? csr[e + 32] : N_NODES;
        h4 v0 = *(const h4*)(hp + (size_t)s0 * 8);
        h4 v1 = *(const h4*)(hp + (size_t)s1 * 8);
        a0 += __low2float(v0.a) + __low2float(v1.a);
        a1 += __high2float(v0.a) + __high2float(v1.a);
        a2 += __low2float(v0.b) + __low2float(v1.b);
        a3 += __high2float(v0.b) + __high2float(v1.b);
    }
    if (eg == 0) {   // self-loop
        h4 v = *(const h4*)(hp + (size_t)node * 8);
        a0 += __low2float(v.a);
        a1 += __high2float(v.a);
        a2 += __low2float(v.b);
        a3 += __high2float(v.b);
    }
#pragma unroll
    for (int off = 2; off < 64; off <<= 1) {
        a0 += __shfl_xor(a0, off, 64);
        a1 += __shfl_xor(a1, off, 64);
        a2 += __shfl_xor(a2, off, 64);
        a3 += __shfl_xor(a3, off, 64);
    }
    float u[8];
    u[0] = __shfl(a0, 0, 64); u[1] = __shfl(a1, 0, 64);
    u[2] = __shfl(a2, 0, 64); u[3] = __shfl(a3, 0, 64);
    u[4] = __shfl(a0, 1, 64); u[5] = __shfl(a1, 1, 64);
    u[6] = __shfl(a2, 1, 64); u[7] = __shfl(a3, 1, 64);
    if (lane < 32) {
        float dn = dis[node];
        float conv = sB[lane] + svec[node] * sC[lane];
#pragma unroll
        for (int i = 0; i < 8; ++i) conv += (dn * u[i]) * sW[i * 32 + lane];
        ys2[(size_t)node * 32 + lane] = __float2half(dn * fmaxf(conv, 0.f));
    }
}

// ---------------- prep3 ----------------

__global__ void k_prep3(const float* __restrict__ stats, const float* __restrict__ gamma,
                        const float* __restrict__ beta, const float* __restrict__ W3,
                        __half* __restrict__ wfrag, float* __restrict__ cw3,
                        __half* __restrict__ ys2) {
    __shared__ float a2[32], c2[32];
    int t = threadIdx.x;   // 512
    if (t < 32) {
        float inv_n = 1.0f / (float)N_NODES;
        float m = stats[t] * inv_n;
        float v = stats[32 + t] * inv_n - m * m;
        float a = gamma[t] * rsqrtf(v + BN_EPS);
        a2[t] = a;
        c2[t] = beta[t] - m * a;
    }
    __syncthreads();
    {
        int g = t >> 6, kq = (t >> 4) & 3, c = t & 15;
#pragma unroll
        for (int j = 0; j < 8; ++j) {
            int k = kq * 8 + j;
            wfrag[(size_t)t * 8 + j] = __float2half(a2[k] * W3[k * 128 + g * 16 + c]);
        }
    }
    if (t < 128) {
        float cb = 0.f;
#pragma unroll
        for (int k = 0; k < 32; ++k) cb += c2[k] * W3[k * 128 + t];
        cw3[t] = cb;
    }
    if (t >= 480 && t < 496)
        ((__half2*)(ys2 + (size_t)N_NODES * 32))[t - 480] =
            __half2{__float2half(0.f), __float2half(0.f)};
}

// ---------------- layer 3 aggregation: ys2 (width 32) -> u2 ----------------

__global__ void k_agg3(const __half* __restrict__ ys2, const int* __restrict__ offs,
                       const int* __restrict__ csr, const float* __restrict__ dis,
                       __half* __restrict__ u2) {
    int wave = threadIdx.x >> 6;
    int lane = threadIdx.x & 63;
    int node = blockIdx.x * 4 + wave;
    if (node >= N_NODES) return;
    int chunk = lane & 7;
    int eg = lane >> 3;
    int e0 = offs[node], e1 = offs[node + 1];
    float ax = 0.f, ay = 0.f, az = 0.f, aw = 0.f;
    const __half* hp = ys2 + (size_t)chunk * 4;
    for (int e = e0 + eg; e < e1; e += 32) {
        int s0 = csr[e];
        int s1 = (e + 8 < e1) ? csr[e + 8] : N_NODES;
        int s2 = (e + 16 < e1) ? csr[e + 16] : N_NODES;
        int s3 = (e + 24 < e1) ? csr[e + 24] : N_NODES;
        h4 v0 = *(const h4*)(hp + (size_t)s0 * 32);
        h4 v1 = *(const h4*)(hp + (size_t)s1 * 32);
        h4 v2 = *(const h4*)(hp + (size_t)s2 * 32);
        h4 v3 = *(const h4*)(hp + (size_t)s3 * 32);
        ax += __low2float(v0.a) + __low2float(v1.a) + __low2float(v2.a) + __low2float(v3.a);
        ay += __high2float(v0.a) + __high2float(v1.a) + __high2float(v2.a) + __high2float(v3.a);
        az += __low2float(v0.b) + __low2float(v1.b) + __low2float(v2.b) + __low2float(v3.b);
        aw += __high2float(v0.b) + __high2float(v1.b) + __high2float(v2.b) + __high2float(v3.b);
    }
    if (eg == 0) {
        h4 v = *(const h4*)(hp + (size_t)node * 32);
        ax += __low2float(v.a);
        ay += __high2float(v.a);
        az += __low2float(v.b);
        aw += __high2float(v.b);
    }
#pragma unroll
    for (int off = 8; off < 64; off <<= 1) {
        ax += __shfl_xor(ax, off, 64);
        ay += __shfl_xor(ay, off, 64);
        az += __shfl_xor(az, off, 64);
        aw += __shfl_xor(aw, off, 64);
    }
    if (lane < 8) {
        float dn = dis[node];
        h4 o;
        o.a = __floats2half2_rn(dn * ax, dn * ay);
        o.b = __floats2half2_rn(dn * az, dn * aw);
        *(h4*)(u2 + (size_t)node * 32 + chunk * 4) = o;
    }
}

// ---------------- layer 3 transform via MFMA ----------------

__global__ void k_mm_mfma(const __half* __restrict__ u2, const __half* __restrict__ wfrag,
                          const float* __restrict__ cw3, const float* __restrict__ b3,
                          const float* __restrict__ svec, const float* __restrict__ dis,
                          __half* __restrict__ ys3) {
    int wave = threadIdx.x >> 6;
    int lane = threadIdx.x & 63;
    int n0 = (blockIdx.x * 4 + wave) * 16;
    if (n0 >= N_NODES) return;
    int m = lane & 15;
    int kq = lane >> 4;

    half8_t af = *(const half8_t*)(u2 + (size_t)(n0 + m) * 32 + kq * 8);

    float4_t accs[8];
#pragma unroll
    for (int g = 0; g < 8; ++g) {
        float4_t acc = {0.f, 0.f, 0.f, 0.f};
        half8_t bf = *(const half8_t*)(wfrag + (size_t)((g * 4 + kq) * 16 + m) * 8);
        accs[g] = __builtin_amdgcn_mfma_f32_16x16x32_f16(af, bf, acc, 0, 0, 0);
    }
    float sv[4], dn[4];
#pragma unroll
    for (int r = 0; r < 4; ++r) {
        sv[r] = svec[n0 + kq * 4 + r];
        dn[r] = dis[n0 + kq * 4 + r];
    }
#pragma unroll
    for (int g = 0; g < 8; ++g) {
        float cwf = cw3[g * 16 + m];
        float bf3 = b3[g * 16 + m];
#pragma unroll
        for (int r = 0; r < 4; ++r) {
            float y = fmaxf(accs[g][r] + sv[r] * cwf + bf3, 0.f);
            ys3[(size_t)(n0 + kq * 4 + r) * 128 + g * 16 + m] = __float2half(dn[r] * y);
        }
    }
}

// ---------------- BN stats over y = ys * rdis (small widths: 8/32) ----------------

template <int FOUT>
__global__ void k_stats(const __half* __restrict__ ys, const float* __restrict__ rdis,
                        float* __restrict__ stats) {
    constexpr int GP = 256 / FOUT;
    int f = threadIdx.x % FOUT, g = threadIdx.x / FOUT;
    float s = 0.f, s2 = 0.f;
    for (int n = blockIdx.x * GP + g; n < N_NODES; n += gridDim.x * GP) {
        float v = __half2float(ys[(size_t)n * FOUT + f]) * rdis[n];
        s += v;
        s2 += v * v;
    }
    __shared__ float ls[256], ls2[256];
    ls[threadIdx.x] = s;
    ls2[threadIdx.x] = s2;
    __syncthreads();
    if (g == 0) {
        for (int gg = 1; gg < GP; ++gg) {
            s += ls[gg * FOUT + f];
            s2 += ls2[gg * FOUT + f];
        }
        atomicAdd(&stats[f], s);
        atomicAdd(&stats[FOUT + f], s2);
    }
}

// ---------------- BN stats width 128: two-phase vectorized ----------------
// phase A: per-slab partials. thread = (row t>>4, chunk t&15); half8 loads.

__global__ void k_stats128(const __half* __restrict__ ys, const float* __restrict__ rdis,
                           float* __restrict__ part) {
    int t = threadIdx.x;
    int chunk = t & 15, row = t >> 4;
    int n0 = blockIdx.x * 128;
    float s[8] = {0, 0, 0, 0, 0, 0, 0, 0};
    float s2[8] = {0, 0, 0, 0, 0, 0, 0, 0};
#pragma unroll
    for (int i = 0; i < 8; ++i) {
        int n = n0 + i * 16 + row;
        if (n < N_NODES) {
            float r = rdis[n];
            h8s v = *(const h8s*)(ys + (size_t)n * 128 + chunk * 8);
#pragma unroll
            for (int q = 0; q < 4; ++q) {
                float v0 = __low2float(v.h[q]) * r;
                float v1 = __high2float(v.h[q]) * r;
                s[2 * q] += v0;  s2[2 * q] += v0 * v0;
                s[2 * q + 1] += v1;  s2[2 * q + 1] += v1 * v1;
            }
        }
    }
    // reduce rows within wave (lane bits 4,5)
#pragma unroll
    for (int off = 16; off < 64; off <<= 1)
#pragma unroll
        for (int j = 0; j < 8; ++j) {
            s[j] += __shfl_xor(s[j], off, 64);
            s2[j] += __shfl_xor(s2[j], off, 64);
        }
    __shared__ float sm[256];
    sm[t] = 0.f;
    __syncthreads();
    if ((t & 63) < 16) {
#pragma unroll
        for (int j = 0; j < 8; ++j) {
            atomicAdd(&sm[chunk * 8 + j], s[j]);
            atomicAdd(&sm[128 + chunk * 8 + j], s2[j]);
        }
    }
    __syncthreads();
    part[(size_t)blockIdx.x * 256 + t] = sm[t];
}

// phase B: reduce partials -> stats (one block per stat entry)
__global__ void k_stats_red(const float* __restrict__ part, float* __restrict__ stats) {
    int i = blockIdx.x;   // 0..255
    int t = threadIdx.x;  // 256
    float s = 0.f;
    for (int b = t; b < NSTATB; b += 256) s += part[(size_t)b * 256 + i];
    __shared__ float sm[256];
    sm[t] = s;
    __syncthreads();
    for (int st = 128; st > 0; st >>= 1) {
        if (t < st) sm[t] += sm[t + st];
        __syncthreads();
    }
    if (t == 0) stats[i] = sm[0];
}

// ---------------- pooling: segment-parallel max/min ----------------

__global__ void k_pool1(const __half* __restrict__ ys3, const float* __restrict__ rdis,
                        const int* __restrict__ batch, int* __restrict__ gmax,
                        int* __restrict__ gmin) {
    __shared__ int sb[LSEG];
    __shared__ float sr[LSEG];
    int n0 = blockIdx.x * LSEG;
    int n1 = min(n0 + LSEG, N_NODES);
    int L = n1 - n0;
    int f = threadIdx.x;    // 128 threads = feature
    for (int i = f; i < L; i += 128) { sb[i] = batch[n0 + i]; sr[i] = rdis[n0 + i]; }
    __syncthreads();
    if (L <= 0) return;
    int cg = sb[0];
    int mx = 0;
    int mn = 0x7F800000;
    for (int i = 0; i < L; ++i) {
        int g = sb[i];
        if (g != cg) {
            atomicMax(&gmax[cg * 128 + f], mx);
            atomicMin(&gmin[cg * 128 + f], mn);
            cg = g; mx = 0; mn = 0x7F800000;
        }
        float v = __half2float(ys3[(size_t)(n0 + i) * 128 + f]) * sr[i];
        int b = __float_as_int(v);
        mx = max(mx, b);
        mn = min(mn, b);
    }
    atomicMax(&gmax[cg * 128 + f], mx);
    atomicMin(&gmin[cg * 128 + f], mn);
}

// ---------------- fused bn-affine + head + log_softmax ----------------

__device__ __forceinline__ int lower_bound_dev(const int* __restrict__ a, int val) {
    int lo = 0, hi = N_NODES;
    while (lo < hi) {
        int mid = (lo + hi) >> 1;
        if (a[mid] < val) lo = mid + 1; else hi = mid;
    }
    return lo;
}

__global__ void k_poolhead(const int* __restrict__ gmax, const int* __restrict__ gmin,
                           const int* __restrict__ batch, const float* __restrict__ stats,
                           const float* __restrict__ gamma, const float* __restrict__ beta,
                           const float* __restrict__ Wl, const float* __restrict__ bl,
                           float* __restrict__ out) {
    int g = blockIdx.x;
    int f = threadIdx.x;    // 128
    float inv_n = 1.0f / (float)N_NODES;
    float m = stats[f] * inv_n;
    float var = stats[128 + f] * inv_n - m * m;
    float a = gamma[f] * rsqrtf(var + BN_EPS);
    float c = beta[f] - m * a;
    int s = lower_bound_dev(batch, g);
    int e = lower_bound_dev(batch, g + 1);
    float mx = __int_as_float(gmax[g * 128 + f]);
    float mn = __int_as_float(gmin[g * 128 + f]);
    float r;
    if (e > s) r = (a >= 0.f) ? (a * mx + c) : (a * mn + c);
    else r = -INFINITY;
    __shared__ float l[3][128];
    l[0][f] = r * Wl[f * 3 + 0];
    l[1][f] = r * Wl[f * 3 + 1];
    l[2][f] = r * Wl[f * 3 + 2];
    __syncthreads();
    for (int st = 64; st > 0; st >>= 1) {
        if (f < st) {
            l[0][f] += l[0][f + st];
            l[1][f] += l[1][f + st];
            l[2][f] += l[2][f + st];
        }
        __syncthreads();
    }
    if (f == 0) {
        float l0 = l[0][0] + bl[0], l1 = l[1][0] + bl[1], l2 = l[2][0] + bl[2];
        float mxl = fmaxf(l0, fmaxf(l1, l2));
        float lse = mxl + logf(expf(l0 - mxl) + expf(l1 - mxl) + expf(l2 - mxl));
        out[g * 3 + 0] = l0 - lse;
        out[g * 3 + 1] = l1 - lse;
        out[g * 3 + 2] = l2 - lse;
    }
}

// ---------------- launch ----------------

extern "C" void kernel_launch(void* const* d_in, const int* in_sizes, int n_in,
                              void* d_out, int out_size, void* d_ws, size_t ws_size,
                              hipStream_t stream) {
    const float* x   = (const float*)d_in[0];
    const int* ei    = (const int*)d_in[1];
    const int* src   = ei;
    const int* dst   = ei + N_EDGES;
    const int* batch = (const int*)d_in[2];
    const float *W1 = (const float*)d_in[3],  *b1 = (const float*)d_in[4];
    const float *g1 = (const float*)d_in[5],  *be1 = (const float*)d_in[6];
    const float *W2 = (const float*)d_in[7],  *b2 = (const float*)d_in[8];
    const float *g2 = (const float*)d_in[9],  *be2 = (const float*)d_in[10];
    const float *W3 = (const float*)d_in[11], *b3 = (const float*)d_in[12];
    const float *g3 = (const float*)d_in[13], *be3 = (const float*)d_in[14];
    const float *Wl = (const float*)d_in[15], *bl = (const float*)d_in[16];
    float* out = (float*)d_out;

    // workspace carve (4-byte words)
    int* base = (int*)d_ws;
    size_t o = 0;
    float* stats1 = (float*)(base + o); o += 256;
    float* stats2 = (float*)(base + o); o += 256;
    float* stats3 = (float*)(base + o); o += 256;
    int* gmax     = base + o; o += (size_t)N_GRAPHS * 128;
    size_t zero_words = o;                         // zeroed region
    int* gmin     = base + o; o += (size_t)N_GRAPHS * 128;   // memset 0x7F
    int* bbase    = base + o; o += 392;
    int* ghist    = base + o; o += 392;
    int* hists    = base + o; o += ((size_t)NBIN * NCHUNK + 3) & ~3ULL;
    float* W2p    = (float*)(base + o); o += 256;
    float* cw2    = (float*)(base + o); o += 32;
    __half* wfrag = (__half*)(base + o); o += 2048;
    float* cw3    = (float*)(base + o); o += 128;
    int* offs     = base + o; o += 100004;
    int* store    = base + o; o += N_EDGES;
    int* csr      = base + o; o += N_EDGES;
    float* dis    = (float*)(base + o); o += N_NODES;
    float* rdis   = (float*)(base + o); o += N_NODES;
    float* svec   = (float*)(base + o); o += N_NODES;
    float* spart  = (float*)(base + o); o += (size_t)NSTATB * 256;
    float4* xd    = (float4*)(base + o); o += (size_t)(N_NODES + 1) * 4;
    __half* ys1   = (__half*)(base + o); o += (size_t)(N_NODES + 1) * 4;
    __half* ys2   = (__half*)(base + o); o += (size_t)(N_NODES + 1) * 16;
    __half* u2    = (__half*)(base + o); o += (size_t)N_NODES * 16;
    __half* ys3   = (__half*)(base + o); o += (size_t)N_NODES * 64;
    if (ws_size < o * 4) return;

    const int TB = 256;
    const int gridAgg = (N_NODES + 3) / 4;

    hipMemsetAsync(base, 0, zero_words * 4, stream);
    hipMemsetAsync(gmin, 0x7F, (size_t)N_GRAPHS * 128 * 4, stream);

    // CSR build
    k_hist2<<<NCHUNK, TB, 0, stream>>>(dst, hists);
    k_scan2<<<NBIN, 64, 0, stream>>>(hists, ghist);
    k_binscan<<<1, 512, 0, stream>>>(ghist, bbase, offs);
    k_scatter<<<NCHUNK, TB, 0, stream>>>(src, dst, bbase, hists, store);
    k_csr_build<<<NBIN, 256, 0, stream>>>(bbase, store, x, offs, dis, rdis, xd, csr);

    // layer 1
    k_agg1<<<gridAgg, TB, 0, stream>>>(xd, offs, csr, W1, b1, svec, ys1);
    k_stats<8><<<256, 256, 0, stream>>>(ys1, rdis, stats1);
    k_prep2<<<1, 256, 0, stream>>>(stats1, g1, be1, W2, W2p, cw2, ys1);

    // layer 2
    k_agg2<<<gridAgg, TB, 0, stream>>>(ys1, offs, csr, dis, svec, W2p, cw2, b2, ys2);
    k_stats<32><<<256, 256, 0, stream>>>(ys2, rdis, stats2);
    k_prep3<<<1, 512, 0, stream>>>(stats2, g2, be2, W3, wfrag, cw3, ys2);

    // layer 3
    k_agg3<<<gridAgg, TB, 0, stream>>>(ys2, offs, csr, dis, u2);
    k_mm_mfma<<<(N_NODES + 63) / 64, 256, 0, stream>>>(u2, wfrag, cw3, b3, svec, dis, ys3);
    k_stats128<<<NSTATB, 256, 0, stream>>>(ys3, rdis, spart);
    k_stats_red<<<256, 256, 0, stream>>>(spart, stats3);

    // pool + head
    k_pool1<<<NSEGB, 128, 0, stream>>>(ys3, rdis, batch, gmax, gmin);
    k_poolhead<<<N_GRAPHS, 128, 0, stream>>>(gmax, gmin, batch, stats3, g3, be3, Wl, bl, out);
}